// Round 2
// baseline (5249.558 us; speedup 1.0000x reference)
//
#include <hip/hip_runtime.h>
#include <math.h>

// Semantic predictor, fp32, spill-free restructure.
// Thread = (sample, token v). 10 samples/wave, 40/block.
// Weights: wave-uniform global loads (SGPR/SMEM path) for transformer; per-lane
// float4 global loads (L1/L2 resident) for the head. Activations: LDS rows
// (stride 33, <=2-way bank alias) so k-loops stay rolled; accumulators in regs.
// Attention k/v row exchange via __shfl. Only 2 __syncthreads (head phase).

#define BLOCK 256
#define SPW   10
#define SPB   40
#define ASTR  33
#define ABFSZ 8000
#define ATTN_SCALE 0.35355339059327373f  // 1/sqrt(8)

__device__ __forceinline__ float elu_f(float x) { return x > 0.f ? x : expm1f(x); }

// acc[32] += a * wrow[0..32)   (wrow: wave-uniform global address)
__device__ __forceinline__ void fma_u32(float* acc, const float* __restrict__ wrow, float a) {
  const float4* w4 = (const float4*)wrow;
#pragma unroll
  for (int jj = 0; jj < 8; ++jj) {
    float4 w = w4[jj];
    acc[4*jj+0] += a * w.x; acc[4*jj+1] += a * w.y;
    acc[4*jj+2] += a * w.z; acc[4*jj+3] += a * w.w;
  }
}

// acc[32] += arow(LDS)[0..32) @ W(32x32, uniform global)
__device__ __forceinline__ void mm_row(float* acc, const float* __restrict__ W, const float* arow) {
#pragma unroll 4
  for (int k = 0; k < 32; ++k) fma_u32(acc, W + k*32, arow[k]);
}

__device__ __forceinline__ void lnorm32(float* x, const float* __restrict__ g, const float* __restrict__ b) {
  float m = 0.f;
#pragma unroll
  for (int d = 0; d < 32; ++d) m += x[d];
  m *= 0.03125f;
  float var = 0.f;
#pragma unroll
  for (int d = 0; d < 32; ++d) { float c = x[d] - m; var += c * c; }
  var *= 0.03125f;
  float r = 1.f / sqrtf(var + 1e-6f);
#pragma unroll
  for (int d = 0; d < 32; ++d) x[d] = (x[d] - m) * r * g[d] + b[d];
}

__global__ __launch_bounds__(BLOCK, 3)
void sem_kernel(const float* __restrict__ feat, const float* __restrict__ occ,
                const float* __restrict__ tokw, const float* __restrict__ tokb,
                const float* __restrict__ wq,   const float* __restrict__ wk,
                const float* __restrict__ wvm,  const float* __restrict__ wom,
                const float* __restrict__ ln1g, const float* __restrict__ ln1b,
                const float* __restrict__ fw1,  const float* __restrict__ fb1,
                const float* __restrict__ fw2,  const float* __restrict__ fb2,
                const float* __restrict__ ln2g, const float* __restrict__ ln2b,
                const float* __restrict__ fc1w, const float* __restrict__ fc1b,
                const float* __restrict__ fc2w, const float* __restrict__ fc2b,
                const float* __restrict__ fc3w, const float* __restrict__ fc3b,
                float* __restrict__ outp, int ntot)
{
  __shared__ float abuf[ABFSZ];

  const int tid  = threadIdx.x;
  const int lane = tid & 63;
  const int wid  = tid >> 6;
  const int siw  = lane / 6;              // 0..10 (10 => idle lanes 60-63)
  const int v    = lane - siw * 6;        // 0..5
  const bool alane = (siw < SPW);
  const int slocal = wid * SPW + (alane ? siw : 0);
  const int n    = blockIdx.x * SPB + slocal;
  const bool act = alane && (n < ntot);
  const int rowoff = (slocal * 6 + v) * ASTR;
  float* row = &abuf[rowoff];
  const int sbase  = siw * 6;             // first lane of this sample

  // ---------------- masks ----------------
  float msk[6];
  {
    float vr6[6], mc6[6];
#pragma unroll
    for (int u = 0; u < 6; ++u) vr6[u] = act ? feat[(n*6 + u)*48 + 47] : 0.f;
    float s0 = vr6[0]+vr6[1]+vr6[2]+vr6[3]+vr6[4]+vr6[5];
#pragma unroll
    for (int u = 0; u < 6; ++u) { vr6[u] = (s0 == 0.f) ? 1.f : vr6[u]; mc6[u] = vr6[u]; }
#pragma unroll
    for (int u = 0; u < 6; ++u) vr6[u] *= act ? occ[n*6 + u] : 0.f;
    float s2 = vr6[0]+vr6[1]+vr6[2]+vr6[3]+vr6[4]+vr6[5];
#pragma unroll
    for (int u = 0; u < 6; ++u) msk[u] = ((s2 == 0.f) ? 1.f : vr6[u]) * mc6[u];
  }

  // ---------------- token embedding ----------------
  float res[32];
  {
    float in21[21];
    if (act) {
      const float* fb = feat + (n*6 + v)*48;
      const float4* fp = (const float4*)(fb + 24);
      float4 s0 = fp[0], s1 = fp[1], s2 = fp[2], s3 = fp[3], s4 = fp[4];
      in21[0] = fb[47];
      in21[1]=s0.x; in21[2]=s0.y; in21[3]=s0.z; in21[4]=s0.w;
      in21[5]=s1.x; in21[6]=s1.y; in21[7]=s1.z; in21[8]=s1.w;
      in21[9]=s2.x; in21[10]=s2.y; in21[11]=s2.z; in21[12]=s2.w;
      in21[13]=s3.x; in21[14]=s3.y; in21[15]=s3.z; in21[16]=s3.w;
      in21[17]=s4.x; in21[18]=s4.y; in21[19]=s4.z; in21[20]=s4.w;
    } else {
#pragma unroll
      for (int j = 0; j < 21; ++j) in21[j] = 0.f;
    }
    float acc[32];
    const float4* tb4 = (const float4*)tokb;
#pragma unroll
    for (int jj = 0; jj < 8; ++jj) {
      float4 b = tb4[jj];
      acc[4*jj+0]=b.x; acc[4*jj+1]=b.y; acc[4*jj+2]=b.z; acc[4*jj+3]=b.w;
    }
#pragma unroll
    for (int j = 0; j < 21; ++j) fma_u32(acc, tokw + j*32, in21[j]);
#pragma unroll
    for (int d = 0; d < 32; ++d) res[d] = elu_f(acc[d]);
    if (alane) {
#pragma unroll
      for (int d = 0; d < 32; ++d) row[d] = res[d];
    }
  }

  // ---------------- transformer layers ----------------
  for (int l = 0; l < 4; ++l) {
    const float* Wq = wq  + (l << 10);
    const float* Wk = wk  + (l << 10);
    const float* Wv = wvm + (l << 10);
    const float* Wo = wom + (l << 10);
    const float* W1 = fw1 + (l << 10);
    const float* W2 = fw2 + (l << 10);

    // q and k rows (from own LDS row, uniform weights)
    float qr[32], kr[32];
#pragma unroll
    for (int d = 0; d < 32; ++d) { qr[d] = 0.f; kr[d] = 0.f; }
#pragma unroll 2
    for (int k = 0; k < 32; ++k) {
      float a = row[k];
      fma_u32(qr, Wq + k*32, a);
      fma_u32(kr, Wk + k*32, a);
    }

    // scores p[h][u] via shuffle of k rows
    float p[4][6];
#pragma unroll
    for (int u = 0; u < 6; ++u) {
      float dh[4] = {0.f, 0.f, 0.f, 0.f};
#pragma unroll
      for (int j = 0; j < 32; ++j) {
        float ku = __shfl(kr[j], sbase + u, 64);
        dh[j >> 3] += qr[j] * ku;
      }
#pragma unroll
      for (int h = 0; h < 4; ++h)
        p[h][u] = (msk[u] == 0.f) ? -INFINITY : dh[h] * ATTN_SCALE;
    }
    // softmax per head
#pragma unroll
    for (int h = 0; h < 4; ++h) {
      float mx = p[h][0];
#pragma unroll
      for (int u = 1; u < 6; ++u) mx = fmaxf(mx, p[h][u]);
      float sum = 0.f;
#pragma unroll
      for (int u = 0; u < 6; ++u) { float e = __expf(p[h][u] - mx); p[h][u] = e; sum += e; }
      float inv = 1.f / sum;
#pragma unroll
      for (int u = 0; u < 6; ++u) p[h][u] *= inv;
    }

    // v rows, then o = attn @ v via shuffle
    float vr[32];
#pragma unroll
    for (int d = 0; d < 32; ++d) vr[d] = 0.f;
#pragma unroll 4
    for (int k = 0; k < 32; ++k) fma_u32(vr, Wv + k*32, row[k]);

    float o[32];
#pragma unroll
    for (int d = 0; d < 32; ++d) o[d] = 0.f;
#pragma unroll
    for (int u = 0; u < 6; ++u) {
#pragma unroll
      for (int j = 0; j < 32; ++j)
        o[j] += p[j >> 3][u] * __shfl(vr[j], sbase + u, 64);
    }
    if (alane) {
#pragma unroll
      for (int d = 0; d < 32; ++d) row[d] = o[d];
    }

    // x = LN1(o @ Wo + res)
    float x[32];
#pragma unroll
    for (int d = 0; d < 32; ++d) x[d] = res[d];
    mm_row(x, Wo, row);
    lnorm32(x, ln1g + l*32, ln1b + l*32);
    if (alane) {
#pragma unroll
      for (int d = 0; d < 32; ++d) row[d] = x[d];
    }

    // h = relu(x @ W1 + b1)
    float hh[32];
#pragma unroll
    for (int d = 0; d < 32; ++d) hh[d] = 0.f;
    mm_row(hh, W1, row);
#pragma unroll
    for (int d = 0; d < 32; ++d) hh[d] = fmaxf(hh[d] + fb1[l*32 + d], 0.f);
    if (alane) {
#pragma unroll
      for (int d = 0; d < 32; ++d) row[d] = hh[d];
    }

    // tokens = LN2(x + h @ W2 + b2)
    float f2[32];
#pragma unroll
    for (int d = 0; d < 32; ++d) f2[d] = x[d] + fb2[l*32 + d];
    mm_row(f2, W2, row);
    lnorm32(f2, ln2g + l*32, ln2b + l*32);
#pragma unroll
    for (int d = 0; d < 32; ++d) res[d] = f2[d];
    if (alane) {
#pragma unroll
      for (int d = 0; d < 32; ++d) row[d] = f2[d];
    }
  }

  // ---------------- head: fc1 (192x192), cols [v*32, v*32+32) ----------------
  float acc1[32];
  {
    const float4* b4 = (const float4*)(fc1b + v*32);
#pragma unroll
    for (int jj = 0; jj < 4; ++jj) { // fc1b has 192; v*32 aligned 16B? v*32*4B -> yes
      float4 b = b4[jj*2], b2v = b4[jj*2+1];
      acc1[8*jj+0]=b.x; acc1[8*jj+1]=b.y; acc1[8*jj+2]=b.z; acc1[8*jj+3]=b.w;
      acc1[8*jj+4]=b2v.x; acc1[8*jj+5]=b2v.y; acc1[8*jj+6]=b2v.z; acc1[8*jj+7]=b2v.w;
    }
#pragma unroll 2
    for (int k = 0; k < 192; ++k) {
      float a = abuf[(slocal*6 + (k >> 5))*ASTR + (k & 31)];
      const float4* w4 = (const float4*)(fc1w + k*192 + v*32);
#pragma unroll
      for (int jj = 0; jj < 8; ++jj) {
        float4 w = w4[jj];
        acc1[4*jj+0] += a * w.x; acc1[4*jj+1] += a * w.y;
        acc1[4*jj+2] += a * w.z; acc1[4*jj+3] += a * w.w;
      }
    }
  }
  __syncthreads();   // all fc1 reads of token rows done before e1 overwrites abuf
  if (alane) {
#pragma unroll
    for (int j = 0; j < 32; ++j) abuf[slocal*199 + v*33 + j] = elu_f(acc1[j]);
  }

  // ---------------- fc2 (192x96), cols [v*16, v*16+16) ----------------
  float acc2[16];
  {
    const float4* b4 = (const float4*)(fc2b + v*16);
#pragma unroll
    for (int jj = 0; jj < 4; ++jj) {
      float4 b = b4[jj];
      acc2[4*jj+0]=b.x; acc2[4*jj+1]=b.y; acc2[4*jj+2]=b.z; acc2[4*jj+3]=b.w;
    }
#pragma unroll 2
    for (int k = 0; k < 192; ++k) {
      float a = abuf[slocal*199 + (k >> 5)*33 + (k & 31)];
      const float4* w4 = (const float4*)(fc2w + k*96 + v*16);
#pragma unroll
      for (int jj = 0; jj < 4; ++jj) {
        float4 w = w4[jj];
        acc2[4*jj+0] += a * w.x; acc2[4*jj+1] += a * w.y;
        acc2[4*jj+2] += a * w.z; acc2[4*jj+3] += a * w.w;
      }
    }
  }
  __syncthreads();   // all fc2 reads of e1 done before e2 overwrites abuf
  if (alane) {
#pragma unroll
    for (int j = 0; j < 16; ++j) abuf[slocal*101 + v*17 + j] = elu_f(acc2[j]);
  }

  // ---------------- fc3 (96x20), lanes v=0..4 compute 4 cols ----------------
  {
    const int cb = (v < 5) ? v*4 : 0;
    float a3[4] = { fc3b[cb], fc3b[cb+1], fc3b[cb+2], fc3b[cb+3] };
#pragma unroll 4
    for (int k = 0; k < 96; ++k) {
      float a = abuf[slocal*101 + (k >> 4)*17 + (k & 15)];
      float4 w = *(const float4*)(fc3w + k*20 + cb);
      a3[0] += a * w.x; a3[1] += a * w.y; a3[2] += a * w.z; a3[3] += a * w.w;
    }
    if (act && v < 5) {
#pragma unroll
      for (int j = 0; j < 4; ++j) outp[n*20 + cb + j] = fmaxf(a3[j], 0.f);
    }
  }
}

extern "C" void kernel_launch(void* const* d_in, const int* in_sizes, int n_in,
                              void* d_out, int out_size, void* d_ws, size_t ws_size,
                              hipStream_t stream)
{
  const float* feat = (const float*)d_in[0];
  const float* occ  = (const float*)d_in[1];
  const float* tokw = (const float*)d_in[2];
  const float* tokb = (const float*)d_in[3];
  const float* wq   = (const float*)d_in[4];
  const float* wk   = (const float*)d_in[5];
  const float* wvm  = (const float*)d_in[6];
  const float* wom  = (const float*)d_in[7];
  const float* ln1g = (const float*)d_in[8];
  const float* ln1b = (const float*)d_in[9];
  const float* fw1  = (const float*)d_in[10];
  const float* fb1  = (const float*)d_in[11];
  const float* fw2  = (const float*)d_in[12];
  const float* fb2  = (const float*)d_in[13];
  const float* ln2g = (const float*)d_in[14];
  const float* ln2b = (const float*)d_in[15];
  const float* fc1w = (const float*)d_in[16];
  const float* fc1b = (const float*)d_in[17];
  const float* fc2w = (const float*)d_in[18];
  const float* fc2b = (const float*)d_in[19];
  const float* fc3w = (const float*)d_in[20];
  const float* fc3b = (const float*)d_in[21];
  float* outp = (float*)d_out;

  const int ntot = in_sizes[0] / 288;
  const int grid = (ntot + SPB - 1) / SPB;
  hipLaunchKernelGGL(sem_kernel, dim3(grid), dim3(BLOCK), 0, stream,
                     feat, occ, tokw, tokb, wq, wk, wvm, wom,
                     ln1g, ln1b, fw1, fb1, fw2, fb2, ln2g, ln2b,
                     fc1w, fc1b, fc2w, fc2b, fc3w, fc3b, outp, ntot);
}

// Round 3
// 1299.048 us; speedup vs baseline: 4.0411x; 4.0411x over previous
//
#include <hip/hip_runtime.h>
#include <math.h>

// Semantic predictor: bf16-MFMA fused transformer + head.
// Block = 16 samples = 96 token rows, 192 threads (3 waves).
// Prep kernel: all GEMM weights -> bf16, transposed to WT[n][k] in d_ws.
// Every 32x32 GEMM tile = ONE mfma_f32_16x16x32_bf16 (K=32 exactly).
// Fragment layouts (m89/m97-verified): A: m=lane&15, k=(lane>>4)*8+j (contig 16B);
// B: n=lane&15, k=(lane>>4)*8+j (from WT, contig 16B); C: n=lane&15, m=(lane>>4)*4+reg.
// LN fused in epilogue via 16-lane __shfl_xor reduction. Attention + fc3 per-lane fp32.

typedef __attribute__((ext_vector_type(8))) short s16x8;
typedef __attribute__((ext_vector_type(4))) float f32x4;

#define SPB   16
#define ROWS  96
#define BSTR  40
#define BLOCK 192
#define ATTN_SCALE 0.35355339059327373f

__device__ __forceinline__ unsigned short f2bf(float x) {
  union { float f; unsigned u; } v; v.f = x;
  unsigned r = v.u + 0x7fff + ((v.u >> 16) & 1);
  return (unsigned short)(r >> 16);
}
__device__ __forceinline__ float bf2f(unsigned short h) {
  union { unsigned u; float f; } v; v.u = ((unsigned)h) << 16;
  return v.f;
}
__device__ __forceinline__ float elu_f(float x) { return x > 0.f ? x : expm1f(x); }

__device__ __forceinline__ f32x4 mfma16(s16x8 a, s16x8 b, f32x4 c) {
  return __builtin_amdgcn_mfma_f32_16x16x32_bf16(a, b, c, 0, 0, 0);
}

// A fragment from LDS row-buffer (stride BSTR bf16): rows m0..m0+15
__device__ __forceinline__ s16x8 ldA(const unsigned short* buf, int m0, int lane) {
  return *(const s16x8*)(buf + (m0 + (lane & 15)) * BSTR + ((lane >> 4) << 3));
}
// B fragment from bf16 WT[n][32] (32x32 matrices)
__device__ __forceinline__ s16x8 ldB32(const unsigned short* wt, int nt, int lane) {
  return *(const s16x8*)(wt + (nt * 16 + (lane & 15)) * 32 + ((lane >> 4) << 3));
}

// ---------------- weight prep: f32 -> bf16, transposed ----------------
__global__ void prep_kernel(const float* __restrict__ wq, const float* __restrict__ wk,
                            const float* __restrict__ wv, const float* __restrict__ wo,
                            const float* __restrict__ w1, const float* __restrict__ w2,
                            const float* __restrict__ fc1w, const float* __restrict__ fc2w,
                            unsigned short* __restrict__ ws)
{
  int i = blockIdx.x * blockDim.x + threadIdx.x;
  int stride = gridDim.x * blockDim.x;
  // [l][mat][n][k] <- mat[l][k][n]
  for (int t = i; t < 24576; t += stride) {
    int lm = t >> 10;
    int l = lm / 6, m = lm - l * 6;
    int j = t & 1023, n = j >> 5, k = j & 31;
    const float* mp;
    if      (m == 0) mp = wq;
    else if (m == 1) mp = wk;
    else if (m == 2) mp = wv;
    else if (m == 3) mp = wo;
    else if (m == 4) mp = w1;
    else             mp = w2;
    ws[t] = f2bf(mp[l * 1024 + k * 32 + n]);
  }
  // fc1: WT1[n(192)][k(192)] <- fc1w[k*192+n]
  for (int t = i; t < 36864; t += stride) {
    int n = t / 192, k = t - n * 192;
    ws[24576 + t] = f2bf(fc1w[k * 192 + n]);
  }
  // fc2: WT2[n(96)][k(192)] <- fc2w[k*96+n]
  for (int t = i; t < 18432; t += stride) {
    int n = t / 192, k = t - n * 192;
    ws[61440 + t] = f2bf(fc2w[k * 96 + n]);
  }
}

// ---------------- main fused kernel ----------------
__global__ __launch_bounds__(BLOCK, 3)
void sem_main(const float* __restrict__ feat, const float* __restrict__ occ,
              const float* __restrict__ tokw, const float* __restrict__ tokb,
              const float* __restrict__ ln1g, const float* __restrict__ ln1b,
              const float* __restrict__ fb1,  const float* __restrict__ fb2,
              const float* __restrict__ ln2g, const float* __restrict__ ln2b,
              const float* __restrict__ fc1b, const float* __restrict__ fc2b,
              const float* __restrict__ fc3w, const float* __restrict__ fc3b,
              const unsigned short* __restrict__ wsq,   // [l][mat][32][32]
              const unsigned short* __restrict__ wt1,   // [192][192]
              const unsigned short* __restrict__ wt2,   // [96][192]
              float* __restrict__ outp, int ntot)
{
  __shared__ unsigned short B0[ROWS * BSTR];
  __shared__ unsigned short B1[ROWS * BSTR];
  __shared__ unsigned short B2[ROWS * BSTR];
  __shared__ unsigned short B3[ROWS * BSTR];
  __shared__ unsigned short P[SPB * 4 * 6 * 6];   // [s][h][q][u] bf16
  __shared__ float msk[SPB][6];

  const int tid  = threadIdx.x;
  const int lane = tid & 63;
  const int wid  = tid >> 6;
  const int sbase = blockIdx.x * SPB;

  // ---- masks (threads 0..15, one sample each) ----
  if (tid < SPB) {
    int n = sbase + tid;
    if (n < ntot) {
      float vr[6], mc[6];
#pragma unroll
      for (int u = 0; u < 6; ++u) vr[u] = feat[(size_t)(n * 6 + u) * 48 + 47];
      float s0 = vr[0]+vr[1]+vr[2]+vr[3]+vr[4]+vr[5];
#pragma unroll
      for (int u = 0; u < 6; ++u) { vr[u] = (s0 == 0.f) ? 1.f : vr[u]; mc[u] = vr[u]; }
#pragma unroll
      for (int u = 0; u < 6; ++u) vr[u] *= occ[n * 6 + u];
      float s2 = vr[0]+vr[1]+vr[2]+vr[3]+vr[4]+vr[5];
#pragma unroll
      for (int u = 0; u < 6; ++u) msk[tid][u] = ((s2 == 0.f) ? 1.f : vr[u]) * mc[u];
    } else {
#pragma unroll
      for (int u = 0; u < 6; ++u) msk[tid][u] = 1.f;
    }
  }

  // ---- token embedding (per-lane fp32): thread = (row, half) ----
  {
    int r = tid >> 1, half = tid & 1;
    int n = sbase + r / 6, v = r - (r / 6) * 6;
    bool ok = (n < ntot);
    float a[21];
    if (ok) {
      const float* fb = feat + (size_t)(n * 6 + v) * 48;
      a[0] = fb[47];
#pragma unroll
      for (int j = 0; j < 20; ++j) a[1 + j] = fb[24 + j];
    } else {
#pragma unroll
      for (int j = 0; j < 21; ++j) a[j] = 0.f;
    }
    int cb = half * 16;
    float acc[16];
#pragma unroll
    for (int j = 0; j < 16; ++j) acc[j] = tokb[cb + j];
#pragma unroll
    for (int k = 0; k < 21; ++k) {
      float av = a[k];
      const float4* w4 = (const float4*)(tokw + k * 32 + cb);
#pragma unroll
      for (int jj = 0; jj < 4; ++jj) {
        float4 w = w4[jj];
        acc[4*jj+0] += av * w.x; acc[4*jj+1] += av * w.y;
        acc[4*jj+2] += av * w.z; acc[4*jj+3] += av * w.w;
      }
    }
#pragma unroll
    for (int j = 0; j < 16; ++j)
      B0[r * BSTR + cb + j] = f2bf(ok ? elu_f(acc[j]) : 0.f);
  }
  __syncthreads();

  // ---- transformer layers ----
  for (int l = 0; l < 4; ++l) {
    const unsigned short* wl = wsq + l * 6144;

    // QKV GEMMs: wave wid owns M-tiles {2w, 2w+1}
#pragma unroll
    for (int t = 0; t < 2; ++t) {
      int m0 = (wid * 2 + t) * 16;
      s16x8 af = ldA(B0, m0, lane);
      int col = lane & 15;
      int r0 = m0 + ((lane >> 4) << 2);
#pragma unroll
      for (int nt = 0; nt < 2; ++nt) {
        f32x4 cq = {0.f,0.f,0.f,0.f}, ck = {0.f,0.f,0.f,0.f}, cv = {0.f,0.f,0.f,0.f};
        cq = mfma16(af, ldB32(wl,        nt, lane), cq);
        ck = mfma16(af, ldB32(wl + 1024, nt, lane), ck);
        cv = mfma16(af, ldB32(wl + 2048, nt, lane), cv);
        int c = nt * 16 + col;
#pragma unroll
        for (int i = 0; i < 4; ++i) {
          B1[(r0 + i) * BSTR + c] = f2bf(cq[i]);
          B2[(r0 + i) * BSTR + c] = f2bf(ck[i]);
          B3[(r0 + i) * BSTR + c] = f2bf(cv[i]);
        }
      }
    }
    __syncthreads();

    // scores + softmax: job = (s, h, q), 384 jobs
    for (int j = tid; j < SPB * 24; j += BLOCK) {
      int s = j / 24, rem = j - s * 24, h = rem / 6, q = rem - h * 6;
      s16x8 qf = *(const s16x8*)(B1 + (s * 6 + q) * BSTR + h * 8);
      float qv[8];
#pragma unroll
      for (int i = 0; i < 8; ++i) qv[i] = bf2f((unsigned short)qf[i]);
      float p6[6];
#pragma unroll
      for (int u = 0; u < 6; ++u) {
        s16x8 kf = *(const s16x8*)(B2 + (s * 6 + u) * BSTR + h * 8);
        float d = 0.f;
#pragma unroll
        for (int i = 0; i < 8; ++i) d += qv[i] * bf2f((unsigned short)kf[i]);
        p6[u] = (msk[s][u] == 0.f) ? -INFINITY : d * ATTN_SCALE;
      }
      float mx = p6[0];
#pragma unroll
      for (int u = 1; u < 6; ++u) mx = fmaxf(mx, p6[u]);
      float sum = 0.f;
#pragma unroll
      for (int u = 0; u < 6; ++u) { float e = __expf(p6[u] - mx); p6[u] = e; sum += e; }
      float inv = 1.f / sum;
      unsigned short* pp = P + ((s * 4 + h) * 6 + q) * 6;
#pragma unroll
      for (int u = 0; u < 6; ++u) pp[u] = f2bf(p6[u] * inv);
    }
    __syncthreads();

    // O = P @ V (per-lane): thread = (row, half); heads {2*half, 2*half+1}
    {
      int r = tid >> 1, half = tid & 1;
      int s = r / 6, q = r - s * 6;
      const unsigned short* pp0 = P + ((s * 4 + half * 2)     * 6 + q) * 6;
      const unsigned short* pp1 = P + ((s * 4 + half * 2 + 1) * 6 + q) * 6;
      float pa[6], pb[6];
#pragma unroll
      for (int u = 0; u < 6; ++u) { pa[u] = bf2f(pp0[u]); pb[u] = bf2f(pp1[u]); }
      float o[16];
#pragma unroll
      for (int i = 0; i < 16; ++i) o[i] = 0.f;
#pragma unroll
      for (int u = 0; u < 6; ++u) {
        const unsigned short* vb = B3 + (s * 6 + u) * BSTR + half * 16;
        s16x8 v0 = *(const s16x8*)(vb);
        s16x8 v1 = *(const s16x8*)(vb + 8);
#pragma unroll
        for (int i = 0; i < 8; ++i) o[i]     += pa[u] * bf2f((unsigned short)v0[i]);
#pragma unroll
        for (int i = 0; i < 8; ++i) o[8 + i] += pb[u] * bf2f((unsigned short)v1[i]);
      }
      __syncthreads();   // Q (B1) fully consumed by scores; safe to overwrite
      int cb = half * 16;
#pragma unroll
      for (int i = 0; i < 16; ++i) B1[r * BSTR + cb + i] = f2bf(o[i]);
    }
    __syncthreads();

    // X = LN1(O @ Wo + T):  A=B1, WT=wl+3072, RES=B0 -> B2
    {
      int c = lane & 15, gq = lane >> 4;
      float g0 = ln1g[l*32 + c], g1 = ln1g[l*32 + c + 16];
      float bb0 = ln1b[l*32 + c], bb1 = ln1b[l*32 + c + 16];
#pragma unroll
      for (int t = 0; t < 2; ++t) {
        int m0 = (wid * 2 + t) * 16;
        s16x8 af = ldA(B1, m0, lane);
        f32x4 c0 = {0.f,0.f,0.f,0.f}, c1 = {0.f,0.f,0.f,0.f};
        c0 = mfma16(af, ldB32(wl + 3072, 0, lane), c0);
        c1 = mfma16(af, ldB32(wl + 3072, 1, lane), c1);
#pragma unroll
        for (int i = 0; i < 4; ++i) {
          int row = m0 + gq * 4 + i;
          float x0 = c0[i] + bf2f(B0[row * BSTR + c]);
          float x1 = c1[i] + bf2f(B0[row * BSTR + c + 16]);
          float s = x0 + x1, ss = x0 * x0 + x1 * x1;
#pragma unroll
          for (int m = 1; m < 16; m <<= 1) {
            s  += __shfl_xor(s,  m, 64);
            ss += __shfl_xor(ss, m, 64);
          }
          float mean = s * 0.03125f;
          float var  = fmaxf(ss * 0.03125f - mean * mean, 0.f);
          float rr   = rsqrtf(var + 1e-6f);
          B2[row * BSTR + c]      = f2bf((x0 - mean) * rr * g0 + bb0);
          B2[row * BSTR + c + 16] = f2bf((x1 - mean) * rr * g1 + bb1);
        }
      }
    }
    __syncthreads();

    // H = relu(X @ W1 + b1):  A=B2, WT=wl+4096 -> B3
    {
      int c = lane & 15, gq = lane >> 4;
      float bi0 = fb1[l*32 + c], bi1 = fb1[l*32 + c + 16];
#pragma unroll
      for (int t = 0; t < 2; ++t) {
        int m0 = (wid * 2 + t) * 16;
        s16x8 af = ldA(B2, m0, lane);
        f32x4 c0 = {0.f,0.f,0.f,0.f}, c1 = {0.f,0.f,0.f,0.f};
        c0 = mfma16(af, ldB32(wl + 4096, 0, lane), c0);
        c1 = mfma16(af, ldB32(wl + 4096, 1, lane), c1);
#pragma unroll
        for (int i = 0; i < 4; ++i) {
          int row = m0 + gq * 4 + i;
          B3[row * BSTR + c]      = f2bf(fmaxf(c0[i] + bi0, 0.f));
          B3[row * BSTR + c + 16] = f2bf(fmaxf(c1[i] + bi1, 0.f));
        }
      }
    }
    __syncthreads();

    // T' = LN2(H @ W2 + b2 + X):  A=B3, WT=wl+5120, RES=B2 -> B0
    {
      int c = lane & 15, gq = lane >> 4;
      float g0 = ln2g[l*32 + c], g1 = ln2g[l*32 + c + 16];
      float bb0 = ln2b[l*32 + c], bb1 = ln2b[l*32 + c + 16];
      float bi0 = fb2[l*32 + c], bi1 = fb2[l*32 + c + 16];
#pragma unroll
      for (int t = 0; t < 2; ++t) {
        int m0 = (wid * 2 + t) * 16;
        s16x8 af = ldA(B3, m0, lane);
        f32x4 c0 = {0.f,0.f,0.f,0.f}, c1 = {0.f,0.f,0.f,0.f};
        c0 = mfma16(af, ldB32(wl + 5120, 0, lane), c0);
        c1 = mfma16(af, ldB32(wl + 5120, 1, lane), c1);
#pragma unroll
        for (int i = 0; i < 4; ++i) {
          int row = m0 + gq * 4 + i;
          float x0 = c0[i] + bi0 + bf2f(B2[row * BSTR + c]);
          float x1 = c1[i] + bi1 + bf2f(B2[row * BSTR + c + 16]);
          float s = x0 + x1, ss = x0 * x0 + x1 * x1;
#pragma unroll
          for (int m = 1; m < 16; m <<= 1) {
            s  += __shfl_xor(s,  m, 64);
            ss += __shfl_xor(ss, m, 64);
          }
          float mean = s * 0.03125f;
          float var  = fmaxf(ss * 0.03125f - mean * mean, 0.f);
          float rr   = rsqrtf(var + 1e-6f);
          B0[row * BSTR + c]      = f2bf((x0 - mean) * rr * g0 + bb0);
          B0[row * BSTR + c + 16] = f2bf((x1 - mean) * rr * g1 + bb1);
        }
      }
    }
    __syncthreads();
  }

  // ---- head fc1: [16,192]@[192,192], wave owns n-tiles 4w..4w+3 -> e1 (=B1, stride 208)
  unsigned short* e1 = B1;
  {
    int c = lane & 15, gq = lane >> 4;
    s16x8 a6[6];
#pragma unroll
    for (int ck = 0; ck < 6; ++ck)
      a6[ck] = *(const s16x8*)(B0 + ((lane & 15) * 6 + ck) * BSTR + ((lane >> 4) << 3));
#pragma unroll
    for (int nt = 0; nt < 4; ++nt) {
      int n0 = (wid * 4 + nt) * 16;
      f32x4 acc = {0.f,0.f,0.f,0.f};
#pragma unroll
      for (int ck = 0; ck < 6; ++ck)
        acc = mfma16(a6[ck], *(const s16x8*)(wt1 + (n0 + c) * 192 + ck * 32 + (gq << 3)), acc);
      float bi = fc1b[n0 + c];
#pragma unroll
      for (int i = 0; i < 4; ++i)
        e1[(gq * 4 + i) * 208 + n0 + c] = f2bf(elu_f(acc[i] + bi));
    }
  }
  __syncthreads();

  // ---- head fc2: [16,192]@[192,96], wave owns n-tiles 2w,2w+1 -> e2 (=B2, stride 104)
  unsigned short* e2 = B2;
  {
    int c = lane & 15, gq = lane >> 4;
    s16x8 a6[6];
#pragma unroll
    for (int ck = 0; ck < 6; ++ck)
      a6[ck] = *(const s16x8*)(e1 + (lane & 15) * 208 + ck * 32 + ((lane >> 4) << 3));
#pragma unroll
    for (int nt = 0; nt < 2; ++nt) {
      int n0 = (wid * 2 + nt) * 16;
      f32x4 acc = {0.f,0.f,0.f,0.f};
#pragma unroll
      for (int ck = 0; ck < 6; ++ck)
        acc = mfma16(a6[ck], *(const s16x8*)(wt2 + (n0 + c) * 192 + ck * 32 + (gq << 3)), acc);
      float bi = fc2b[n0 + c];
#pragma unroll
      for (int i = 0; i < 4; ++i)
        e2[(gq * 4 + i) * 104 + n0 + c] = f2bf(elu_f(acc[i] + bi));
    }
  }
  __syncthreads();

  // ---- head fc3: [16,96]@[96,20] per-lane fp32, relu, store ----
  for (int j = tid; j < SPB * 20; j += BLOCK) {
    int s = j / 20, cc = j - s * 20;
    int n = sbase + s;
    if (n < ntot) {
      float acc = fc3b[cc];
#pragma unroll 8
      for (int k = 0; k < 96; ++k)
        acc += bf2f(e2[s * 104 + k]) * fc3w[k * 20 + cc];
      outp[(size_t)n * 20 + cc] = fmaxf(acc, 0.f);
    }
  }
}

extern "C" void kernel_launch(void* const* d_in, const int* in_sizes, int n_in,
                              void* d_out, int out_size, void* d_ws, size_t ws_size,
                              hipStream_t stream)
{
  const float* feat = (const float*)d_in[0];
  const float* occ  = (const float*)d_in[1];
  const float* tokw = (const float*)d_in[2];
  const float* tokb = (const float*)d_in[3];
  const float* wq   = (const float*)d_in[4];
  const float* wk   = (const float*)d_in[5];
  const float* wv   = (const float*)d_in[6];
  const float* wo   = (const float*)d_in[7];
  const float* ln1g = (const float*)d_in[8];
  const float* ln1b = (const float*)d_in[9];
  const float* fw1  = (const float*)d_in[10];
  const float* fb1  = (const float*)d_in[11];
  const float* fw2  = (const float*)d_in[12];
  const float* fb2  = (const float*)d_in[13];
  const float* ln2g = (const float*)d_in[14];
  const float* ln2b = (const float*)d_in[15];
  const float* fc1w = (const float*)d_in[16];
  const float* fc1b = (const float*)d_in[17];
  const float* fc2w = (const float*)d_in[18];
  const float* fc2b = (const float*)d_in[19];
  const float* fc3w = (const float*)d_in[20];
  const float* fc3b = (const float*)d_in[21];
  float* outp = (float*)d_out;

  unsigned short* ws = (unsigned short*)d_ws;
  const int ntot = in_sizes[0] / 288;

  hipLaunchKernelGGL(prep_kernel, dim3(128), dim3(256), 0, stream,
                     wq, wk, wv, wo, fw1, fw2, fc1w, fc2w, ws);

  const int grid = (ntot + SPB - 1) / SPB;
  hipLaunchKernelGGL(sem_main, dim3(grid), dim3(BLOCK), 0, stream,
                     feat, occ, tokw, tokb, ln1g, ln1b, fb1, fb2, ln2g, ln2b,
                     fc1b, fc2b, fc3w, fc3b,
                     ws, ws + 24576, ws + 61440, outp, ntot);
}

// Round 4
// 873.508 us; speedup vs baseline: 6.0097x; 1.4872x over previous
//
#include <hip/hip_runtime.h>
#include <math.h>

// Semantic predictor: wave-local bf16-MFMA transformer + fused MFMA head.
// Samples padded 6->8 rows: 2 samples = one 16-row M-tile = one wave's private job.
// Transformer phases are barrier-free (wave-private LDS slices, lgkmcnt ordering).
// Head: block = 16 samples = M=16 tile; fc1/fc2 MFMA over 8 waves; 3 barriers total.

typedef __attribute__((ext_vector_type(8))) short s16x8;
typedef __attribute__((ext_vector_type(4))) float f32x4;

#define ATTN_SCALE 0.35355339059327373f
#define WSLICE 648   // wave LDS slice stride in shorts (1296B; 324 dw % 32 = 4 -> 2-way max)

__device__ __forceinline__ unsigned short f2bf(float x) {
  union { float f; unsigned u; } v; v.f = x;
  unsigned r = v.u + 0x7fff + ((v.u >> 16) & 1);
  return (unsigned short)(r >> 16);
}
__device__ __forceinline__ float bf2f(unsigned short h) {
  union { unsigned u; float f; } v; v.u = ((unsigned)h) << 16;
  return v.f;
}
__device__ __forceinline__ float elu_f(float x) { return x > 0.f ? x : expm1f(x); }

__device__ __forceinline__ f32x4 mfma16(s16x8 a, s16x8 b, f32x4 c) {
  return __builtin_amdgcn_mfma_f32_16x16x32_bf16(a, b, c, 0, 0, 0);
}
// B fragment from bf16 WT[n][32]: n = nt*16 + (lane&15), k = (lane>>4)*8..+8
__device__ __forceinline__ s16x8 ldB32(const unsigned short* __restrict__ wt, int nt, int c, int gq) {
  return *(const s16x8*)(wt + (nt * 16 + c) * 32 + (gq << 3));
}

// ---------------- weight prep: f32 -> bf16, transposed ----------------
__global__ void prep_kernel(const float* __restrict__ wq, const float* __restrict__ wk,
                            const float* __restrict__ wv, const float* __restrict__ wo,
                            const float* __restrict__ w1, const float* __restrict__ w2,
                            const float* __restrict__ fc1w, const float* __restrict__ fc2w,
                            unsigned short* __restrict__ ws)
{
  int i = blockIdx.x * blockDim.x + threadIdx.x;
  int stride = gridDim.x * blockDim.x;
  for (int t = i; t < 24576; t += stride) {       // [l][mat][n][k] <- mat[l][k][n]
    int lm = t >> 10;
    int l = lm / 6, m = lm - l * 6;
    int j = t & 1023, n = j >> 5, k = j & 31;
    const float* mp;
    if      (m == 0) mp = wq;
    else if (m == 1) mp = wk;
    else if (m == 2) mp = wv;
    else if (m == 3) mp = wo;
    else if (m == 4) mp = w1;
    else             mp = w2;
    ws[t] = f2bf(mp[l * 1024 + k * 32 + n]);
  }
  for (int t = i; t < 36864; t += stride) {       // WT1[n(192)][k(192)]
    int n = t / 192, k = t - n * 192;
    ws[24576 + t] = f2bf(fc1w[k * 192 + n]);
  }
  for (int t = i; t < 18432; t += stride) {       // WT2[n(96)][k(192)]
    int n = t / 192, k = t - n * 192;
    ws[61440 + t] = f2bf(fc2w[k * 96 + n]);
  }
}

// ---------------- main fused kernel ----------------
__global__ __launch_bounds__(512, 2)
void sem_main(const float* __restrict__ feat, const float* __restrict__ occ,
              const float* __restrict__ tokw, const float* __restrict__ tokb,
              const float* __restrict__ ln1g, const float* __restrict__ ln1b,
              const float* __restrict__ fb1,  const float* __restrict__ fb2,
              const float* __restrict__ ln2g, const float* __restrict__ ln2b,
              const float* __restrict__ fc1b, const float* __restrict__ fc2b,
              const float* __restrict__ fc3w, const float* __restrict__ fc3b,
              const unsigned short* __restrict__ wsq,   // [l][mat][32][32]
              const unsigned short* __restrict__ wt1,   // [192][192]
              const unsigned short* __restrict__ wt2,   // [96][192]
              float* __restrict__ outp, int ntot)
{
  // wave-private activation slices (16 rows x stride 40, rows = sample*8+v)
  __shared__ unsigned short SB0[8 * WSLICE];
  __shared__ unsigned short SB1[8 * WSLICE];
  __shared__ unsigned short SB2[8 * WSLICE];
  __shared__ unsigned short SB3[8 * WSLICE];
  __shared__ float mskS[8][12];
  __shared__ unsigned short e1[16 * 200];
  __shared__ unsigned short e2[16 * 104];

  const int tid  = threadIdx.x;
  const int lane = tid & 63;
  const int wid  = tid >> 6;
  const int c    = lane & 15;
  const int gq   = lane >> 4;
  const int n0b  = blockIdx.x * 16;       // block sample base
  const int n0   = n0b + wid * 2;         // wave sample base (2 samples)

  unsigned short* B0 = SB0 + wid * WSLICE;
  unsigned short* B1 = SB1 + wid * WSLICE;
  unsigned short* B2 = SB2 + wid * WSLICE;
  unsigned short* B3 = SB3 + wid * WSLICE;

  // ---- masks: lanes 0,1 each handle one sample ----
  if (lane < 2) {
    int n = n0 + lane;
    float m6[6];
    if (n < ntot) {
      float vr[6], mc[6];
#pragma unroll
      for (int u = 0; u < 6; ++u) vr[u] = feat[(size_t)(n * 6 + u) * 48 + 47];
      float s0 = vr[0]+vr[1]+vr[2]+vr[3]+vr[4]+vr[5];
#pragma unroll
      for (int u = 0; u < 6; ++u) { vr[u] = (s0 == 0.f) ? 1.f : vr[u]; mc[u] = vr[u]; }
#pragma unroll
      for (int u = 0; u < 6; ++u) vr[u] *= occ[n * 6 + u];
      float s2 = vr[0]+vr[1]+vr[2]+vr[3]+vr[4]+vr[5];
#pragma unroll
      for (int u = 0; u < 6; ++u) m6[u] = ((s2 == 0.f) ? 1.f : vr[u]) * mc[u];
    } else {
#pragma unroll
      for (int u = 0; u < 6; ++u) m6[u] = 1.f;
    }
#pragma unroll
    for (int u = 0; u < 6; ++u) mskS[wid][lane * 6 + u] = m6[u];
  }

  // ---- token embedding: 12 real rows x 4 col-quarters = 48 lane jobs ----
  if (lane < 48) {
    int r12 = lane >> 2, q8 = lane & 3;
    int s = r12 / 6, v = r12 - s * 6;
    int n = n0 + s;
    float a[21];
    if (n < ntot) {
      const float* fb = feat + (size_t)(n * 6 + v) * 48;
      const float4* fp = (const float4*)(fb + 24);
      float4 f0 = fp[0], f1 = fp[1], f2v = fp[2], f3 = fp[3], f4 = fp[4];
      a[0] = fb[47];
      a[1]=f0.x; a[2]=f0.y; a[3]=f0.z; a[4]=f0.w;
      a[5]=f1.x; a[6]=f1.y; a[7]=f1.z; a[8]=f1.w;
      a[9]=f2v.x; a[10]=f2v.y; a[11]=f2v.z; a[12]=f2v.w;
      a[13]=f3.x; a[14]=f3.y; a[15]=f3.z; a[16]=f3.w;
      a[17]=f4.x; a[18]=f4.y; a[19]=f4.z; a[20]=f4.w;
    } else {
#pragma unroll
      for (int j = 0; j < 21; ++j) a[j] = 0.f;
    }
    float acc[8];
    {
      const float4* b4 = (const float4*)(tokb + q8 * 8);
      float4 b0 = b4[0], b1v = b4[1];
      acc[0]=b0.x; acc[1]=b0.y; acc[2]=b0.z; acc[3]=b0.w;
      acc[4]=b1v.x; acc[5]=b1v.y; acc[6]=b1v.z; acc[7]=b1v.w;
    }
#pragma unroll
    for (int k = 0; k < 21; ++k) {
      float av = a[k];
      const float4* w4 = (const float4*)(tokw + k * 32 + q8 * 8);
      float4 w0 = w4[0], w1v = w4[1];
      acc[0] += av * w0.x; acc[1] += av * w0.y; acc[2] += av * w0.z; acc[3] += av * w0.w;
      acc[4] += av * w1v.x; acc[5] += av * w1v.y; acc[6] += av * w1v.z; acc[7] += av * w1v.w;
    }
    unsigned short* dst = B0 + (s * 8 + v) * 40 + q8 * 8;
#pragma unroll
    for (int j = 0; j < 8; ++j) dst[j] = f2bf(elu_f(acc[j]));
  } else {
    // zero the 4 padding rows (6,7,14,15)
    int idx = lane - 48;               // 0..15
    int pr = idx >> 2, q8 = idx & 3;
    int row = (pr >> 1) * 8 + 6 + (pr & 1);
    unsigned short* dst = B0 + row * 40 + q8 * 8;
#pragma unroll
    for (int j = 0; j < 8; ++j) dst[j] = 0;
  }
  __builtin_amdgcn_wave_barrier();

  // ---- transformer layers (barrier-free, wave-local) ----
  for (int l = 0; l < 4; ++l) {
    const unsigned short* wl = wsq + l * 6144;

    // QKV: one M-tile, 6 MFMAs
    {
      s16x8 a = *(const s16x8*)(B0 + c * 40 + (gq << 3));
      f32x4 cq0 = {0.f,0.f,0.f,0.f}, cq1 = cq0, ck0 = cq0, ck1 = cq0, cv0 = cq0, cv1 = cq0;
      cq0 = mfma16(a, ldB32(wl,        0, c, gq), cq0);
      cq1 = mfma16(a, ldB32(wl,        1, c, gq), cq1);
      ck0 = mfma16(a, ldB32(wl + 1024, 0, c, gq), ck0);
      ck1 = mfma16(a, ldB32(wl + 1024, 1, c, gq), ck1);
      cv0 = mfma16(a, ldB32(wl + 2048, 0, c, gq), cv0);
      cv1 = mfma16(a, ldB32(wl + 2048, 1, c, gq), cv1);
#pragma unroll
      for (int i = 0; i < 4; ++i) {
        int ro = (gq * 4 + i) * 40;
        B1[ro + c] = f2bf(cq0[i]); B1[ro + c + 16] = f2bf(cq1[i]);
        B2[ro + c] = f2bf(ck0[i]); B2[ro + c + 16] = f2bf(ck1[i]);
        B3[ro + c] = f2bf(cv0[i]); B3[ro + c + 16] = f2bf(cv1[i]);
      }
    }
    __builtin_amdgcn_wave_barrier();

    // attention: 48 lane jobs (s, q, h): per-head scores+softmax+PV
    if (lane < 48) {
      int s = lane / 24, t = lane - s * 24, q = t >> 2, h = t & 3;
      s16x8 qf = *(const s16x8*)(B1 + (s * 8 + q) * 40 + h * 8);
      float qv[8];
#pragma unroll
      for (int i = 0; i < 8; ++i) qv[i] = bf2f((unsigned short)qf[i]);
      float p6[6];
#pragma unroll
      for (int u = 0; u < 6; ++u) {
        s16x8 kf = *(const s16x8*)(B2 + (s * 8 + u) * 40 + h * 8);
        float d = 0.f;
#pragma unroll
        for (int i = 0; i < 8; ++i) d += qv[i] * bf2f((unsigned short)kf[i]);
        p6[u] = (mskS[wid][s * 6 + u] == 0.f) ? -INFINITY : d * ATTN_SCALE;
      }
      float mx = p6[0];
#pragma unroll
      for (int u = 1; u < 6; ++u) mx = fmaxf(mx, p6[u]);
      float sum = 0.f;
#pragma unroll
      for (int u = 0; u < 6; ++u) { float e = __expf(p6[u] - mx); p6[u] = e; sum += e; }
      float inv = 1.f / sum;
      float o[8];
#pragma unroll
      for (int i = 0; i < 8; ++i) o[i] = 0.f;
#pragma unroll
      for (int u = 0; u < 6; ++u) {
        s16x8 vf = *(const s16x8*)(B3 + (s * 8 + u) * 40 + h * 8);
        float pw = p6[u] * inv;
#pragma unroll
        for (int i = 0; i < 8; ++i) o[i] += pw * bf2f((unsigned short)vf[i]);
      }
      unsigned short* op = B1 + (s * 8 + q) * 40 + h * 8;   // overwrite own Q slot
#pragma unroll
      for (int i = 0; i < 8; ++i) op[i] = f2bf(o[i]);
    }
    __builtin_amdgcn_wave_barrier();

    // X = LN1(O @ Wo + res[B0]) -> B2
    {
      s16x8 a = *(const s16x8*)(B1 + c * 40 + (gq << 3));
      f32x4 c0 = {0.f,0.f,0.f,0.f}, c1 = c0;
      c0 = mfma16(a, ldB32(wl + 3072, 0, c, gq), c0);
      c1 = mfma16(a, ldB32(wl + 3072, 1, c, gq), c1);
      float g0 = ln1g[l*32 + c], g1 = ln1g[l*32 + c + 16];
      float bb0 = ln1b[l*32 + c], bb1 = ln1b[l*32 + c + 16];
#pragma unroll
      for (int i = 0; i < 4; ++i) {
        int row = gq * 4 + i;
        float x0 = c0[i] + bf2f(B0[row * 40 + c]);
        float x1 = c1[i] + bf2f(B0[row * 40 + c + 16]);
        float s = x0 + x1, ss = x0 * x0 + x1 * x1;
#pragma unroll
        for (int m = 1; m < 16; m <<= 1) {
          s  += __shfl_xor(s,  m, 64);
          ss += __shfl_xor(ss, m, 64);
        }
        float mean = s * 0.03125f;
        float var  = fmaxf(ss * 0.03125f - mean * mean, 0.f);
        float rr   = rsqrtf(var + 1e-6f);
        B2[row * 40 + c]      = f2bf((x0 - mean) * rr * g0 + bb0);
        B2[row * 40 + c + 16] = f2bf((x1 - mean) * rr * g1 + bb1);
      }
    }
    __builtin_amdgcn_wave_barrier();

    // H = relu(X @ W1 + b1) -> B3
    {
      s16x8 a = *(const s16x8*)(B2 + c * 40 + (gq << 3));
      f32x4 c0 = {0.f,0.f,0.f,0.f}, c1 = c0;
      c0 = mfma16(a, ldB32(wl + 4096, 0, c, gq), c0);
      c1 = mfma16(a, ldB32(wl + 4096, 1, c, gq), c1);
      float bi0 = fb1[l*32 + c], bi1 = fb1[l*32 + c + 16];
#pragma unroll
      for (int i = 0; i < 4; ++i) {
        int row = gq * 4 + i;
        B3[row * 40 + c]      = f2bf(fmaxf(c0[i] + bi0, 0.f));
        B3[row * 40 + c + 16] = f2bf(fmaxf(c1[i] + bi1, 0.f));
      }
    }
    __builtin_amdgcn_wave_barrier();

    // T' = LN2(H @ W2 + b2 + X[B2]) -> B0
    {
      s16x8 a = *(const s16x8*)(B3 + c * 40 + (gq << 3));
      f32x4 c0 = {0.f,0.f,0.f,0.f}, c1 = c0;
      c0 = mfma16(a, ldB32(wl + 5120, 0, c, gq), c0);
      c1 = mfma16(a, ldB32(wl + 5120, 1, c, gq), c1);
      float g0 = ln2g[l*32 + c], g1 = ln2g[l*32 + c + 16];
      float bb0 = ln2b[l*32 + c], bb1 = ln2b[l*32 + c + 16];
      float bi0 = fb2[l*32 + c], bi1 = fb2[l*32 + c + 16];
#pragma unroll
      for (int i = 0; i < 4; ++i) {
        int row = gq * 4 + i;
        float x0 = c0[i] + bi0 + bf2f(B2[row * 40 + c]);
        float x1 = c1[i] + bi1 + bf2f(B2[row * 40 + c + 16]);
        float s = x0 + x1, ss = x0 * x0 + x1 * x1;
#pragma unroll
        for (int m = 1; m < 16; m <<= 1) {
          s  += __shfl_xor(s,  m, 64);
          ss += __shfl_xor(ss, m, 64);
        }
        float mean = s * 0.03125f;
        float var  = fmaxf(ss * 0.03125f - mean * mean, 0.f);
        float rr   = rsqrtf(var + 1e-6f);
        B0[row * 40 + c]      = f2bf((x0 - mean) * rr * g0 + bb0);
        B0[row * 40 + c + 16] = f2bf((x1 - mean) * rr * g1 + bb1);
      }
    }
    __builtin_amdgcn_wave_barrier();
  }

  // ---- head: block = 16 samples = one M=16 tile ----
  __syncthreads();   // token state (all SB0 wave slices) visible block-wide

  // A-frags for fc1: sample = n0b + c, k = ck*32 + gq*8  (k dim: v=ck, col=gq*8..)
  s16x8 a6[6];
#pragma unroll
  for (int ck = 0; ck < 6; ++ck)
    a6[ck] = *(const s16x8*)(SB0 + (c >> 1) * WSLICE + ((c & 1) * 8 + ck) * 40 + (gq << 3));

  // fc1: 12 n-tiles over 8 waves (wave w: nt = w, and w+8 if w<4)
  {
    int nt = wid;
    f32x4 acc = {0.f,0.f,0.f,0.f};
#pragma unroll
    for (int ck = 0; ck < 6; ++ck)
      acc = mfma16(a6[ck], *(const s16x8*)(wt1 + (nt*16 + c) * 192 + ck*32 + (gq << 3)), acc);
    float bi = fc1b[nt * 16 + c];
#pragma unroll
    for (int i = 0; i < 4; ++i)
      e1[(gq * 4 + i) * 200 + nt * 16 + c] = f2bf(elu_f(acc[i] + bi));
    if (wid < 4) {
      nt = wid + 8;
      f32x4 acc2 = {0.f,0.f,0.f,0.f};
#pragma unroll
      for (int ck = 0; ck < 6; ++ck)
        acc2 = mfma16(a6[ck], *(const s16x8*)(wt1 + (nt*16 + c) * 192 + ck*32 + (gq << 3)), acc2);
      float bi2 = fc1b[nt * 16 + c];
#pragma unroll
      for (int i = 0; i < 4; ++i)
        e1[(gq * 4 + i) * 200 + nt * 16 + c] = f2bf(elu_f(acc2[i] + bi2));
    }
  }
  __syncthreads();

  // fc2: 6 n-tiles over waves 0..5
  if (wid < 6) {
    s16x8 h6[6];
#pragma unroll
    for (int ck = 0; ck < 6; ++ck)
      h6[ck] = *(const s16x8*)(e1 + c * 200 + ck * 32 + (gq << 3));
    int nt = wid;
    f32x4 acc = {0.f,0.f,0.f,0.f};
#pragma unroll
    for (int ck = 0; ck < 6; ++ck)
      acc = mfma16(h6[ck], *(const s16x8*)(wt2 + (nt*16 + c) * 192 + ck*32 + (gq << 3)), acc);
    float bi = fc2b[nt * 16 + c];
#pragma unroll
    for (int i = 0; i < 4; ++i)
      e2[(gq * 4 + i) * 104 + nt * 16 + c] = f2bf(elu_f(acc[i] + bi));
  }
  __syncthreads();

  // fc3: 320 jobs (sample, col)
  if (tid < 320) {
    int s = tid / 20, cc = tid - s * 20;
    int n = n0b + s;
    float acc = fc3b[cc];
#pragma unroll 4
    for (int k = 0; k < 96; ++k)
      acc += bf2f(e2[s * 104 + k]) * fc3w[k * 20 + cc];
    if (n < ntot) outp[(size_t)n * 20 + cc] = fmaxf(acc, 0.f);
  }
}

extern "C" void kernel_launch(void* const* d_in, const int* in_sizes, int n_in,
                              void* d_out, int out_size, void* d_ws, size_t ws_size,
                              hipStream_t stream)
{
  const float* feat = (const float*)d_in[0];
  const float* occ  = (const float*)d_in[1];
  const float* tokw = (const float*)d_in[2];
  const float* tokb = (const float*)d_in[3];
  const float* wq   = (const float*)d_in[4];
  const float* wk   = (const float*)d_in[5];
  const float* wv   = (const float*)d_in[6];
  const float* wo   = (const float*)d_in[7];
  const float* ln1g = (const float*)d_in[8];
  const float* ln1b = (const float*)d_in[9];
  const float* fw1  = (const float*)d_in[10];
  const float* fb1  = (const float*)d_in[11];
  const float* fw2  = (const float*)d_in[12];
  const float* fb2  = (const float*)d_in[13];
  const float* ln2g = (const float*)d_in[14];
  const float* ln2b = (const float*)d_in[15];
  const float* fc1w = (const float*)d_in[16];
  const float* fc1b = (const float*)d_in[17];
  const float* fc2w = (const float*)d_in[18];
  const float* fc2b = (const float*)d_in[19];
  const float* fc3w = (const float*)d_in[20];
  const float* fc3b = (const float*)d_in[21];
  float* outp = (float*)d_out;

  unsigned short* ws = (unsigned short*)d_ws;
  const int ntot = in_sizes[0] / 288;

  hipLaunchKernelGGL(prep_kernel, dim3(128), dim3(256), 0, stream,
                     wq, wk, wv, wo, fw1, fw2, fc1w, fc2w, ws);

  const int grid = (ntot + 15) / 16;
  hipLaunchKernelGGL(sem_main, dim3(grid), dim3(512), 0, stream,
                     feat, occ, tokw, tokb, ln1g, ln1b, fb1, fb2, ln2g, ln2b,
                     fc1b, fc2b, fc3w, fc3b,
                     ws, ws + 24576, ws + 61440, outp, ntot);
}

// Round 6
// 500.219 us; speedup vs baseline: 10.4945x; 1.7463x over previous
//
#include <hip/hip_runtime.h>
#include <hip/hip_bf16.h>
#include <math.h>

// Semantic predictor: wave-local bf16-MFMA transformer + fused MFMA head.
// 2 samples (12 real + 4 pad rows) = one 16-row M-tile per wave; barrier-free
// transformer phases (wave-private LDS slices). Conversions via compiler
// __float2bfloat16 (native cvt). wtok/wt3 built per-block in LDS so d_ws
// usage stays at the proven 159,744 B (rounds 3/4 passed at this size).

typedef __attribute__((ext_vector_type(8))) short s16x8;
typedef __attribute__((ext_vector_type(4))) float f32x4;

#define ATTN_SCALE 0.35355339059327373f
#define WSLICE 648   // wave LDS slice stride in shorts

__device__ __forceinline__ unsigned short bfc(float x) {
  __hip_bfloat16 h = __float2bfloat16(x);
  return __builtin_bit_cast(unsigned short, h);
}
__device__ __forceinline__ float fbc(unsigned short u) {
  union { unsigned v; float f; } w; w.v = ((unsigned)u) << 16;
  return w.f;
}
__device__ __forceinline__ float elu_f(float x) { return x > 0.f ? x : __expf(x) - 1.f; }

__device__ __forceinline__ f32x4 mfma16(s16x8 a, s16x8 b, f32x4 c) {
  return __builtin_amdgcn_mfma_f32_16x16x32_bf16(a, b, c, 0, 0, 0);
}
// B fragment from bf16 WT[n][32]: n = nt*16 + c, k = gq*8..+8
__device__ __forceinline__ s16x8 ldB32(const unsigned short* __restrict__ wt, int nt, int c, int gq) {
  return *(const s16x8*)(wt + (nt * 16 + c) * 32 + (gq << 3));
}

// ---------------- weight prep: f32 -> bf16, transposed (159,744 B total) ----------------
__global__ void prep_kernel(const float* __restrict__ wq, const float* __restrict__ wk,
                            const float* __restrict__ wv, const float* __restrict__ wo,
                            const float* __restrict__ w1, const float* __restrict__ w2,
                            const float* __restrict__ fc1w, const float* __restrict__ fc2w,
                            unsigned short* __restrict__ ws)
{
  int i = blockIdx.x * blockDim.x + threadIdx.x;
  int stride = gridDim.x * blockDim.x;
  for (int t = i; t < 24576; t += stride) {       // [l][mat][n][k] <- mat[l][k][n]
    int lm = t >> 10;
    int l = lm / 6, m = lm - l * 6;
    int j = t & 1023, n = j >> 5, k = j & 31;
    const float* mp;
    if      (m == 0) mp = wq;
    else if (m == 1) mp = wk;
    else if (m == 2) mp = wv;
    else if (m == 3) mp = wo;
    else if (m == 4) mp = w1;
    else             mp = w2;
    ws[t] = bfc(mp[l * 1024 + k * 32 + n]);
  }
  for (int t = i; t < 36864; t += stride) {       // WT1[n(192)][k(192)]
    int n = t / 192, k = t - n * 192;
    ws[24576 + t] = bfc(fc1w[k * 192 + n]);
  }
  for (int t = i; t < 18432; t += stride) {       // WT2[n(96)][k(192)]
    int n = t / 192, k = t - n * 192;
    ws[61440 + t] = bfc(fc2w[k * 96 + n]);
  }
}

// ---------------- main fused kernel ----------------
__global__ __launch_bounds__(512, 2)
void sem_main(const float* __restrict__ feat, const float* __restrict__ occ,
              const float* __restrict__ tokw, const float* __restrict__ tokb,
              const float* __restrict__ ln1g, const float* __restrict__ ln1b,
              const float* __restrict__ fb1,  const float* __restrict__ fb2,
              const float* __restrict__ ln2g, const float* __restrict__ ln2b,
              const float* __restrict__ fc1b, const float* __restrict__ fc2b,
              const float* __restrict__ fc3w, const float* __restrict__ fc3b,
              const unsigned short* __restrict__ wsq,   // [l][mat][32][32]
              const unsigned short* __restrict__ wt1,   // [192][192]
              const unsigned short* __restrict__ wt2,   // [96][192]
              float* __restrict__ outp, int ntot)
{
  __shared__ unsigned short SB0[8 * WSLICE];
  __shared__ unsigned short SB1[8 * WSLICE];
  __shared__ unsigned short SB2[8 * WSLICE];
  __shared__ unsigned short SB3[8 * WSLICE];
  __shared__ float mskS[8][12];
  __shared__ unsigned short e1[16 * 200];
  __shared__ unsigned short e2[16 * 104];
  __shared__ unsigned short WTL[3072];   // wtok[32][32] early; wt3[32][96] late

  const int tid  = threadIdx.x;
  const int lane = tid & 63;
  const int wid  = tid >> 6;
  const int c    = lane & 15;
  const int gq   = lane >> 4;
  const int n0b  = blockIdx.x * 16;
  const int n0   = n0b + wid * 2;

  unsigned short* B0 = SB0 + wid * WSLICE;
  unsigned short* B1 = SB1 + wid * WSLICE;
  unsigned short* B2 = SB2 + wid * WSLICE;
  unsigned short* B3 = SB3 + wid * WSLICE;

  // ---- stage wtok -> WTL[0..1024): WT_tok[n][32], k>=21 zero ----
  for (int t = tid; t < 1024; t += 512) {
    int n = t >> 5, k = t & 31;
    WTL[t] = (k < 21) ? bfc(tokw[k * 32 + n]) : (unsigned short)0;
  }

  // ---- masks: lanes 0,1 each handle one sample ----
  if (lane < 2) {
    int n = n0 + lane;
    float m6[6];
    if (n < ntot) {
      float vr[6], mc[6];
#pragma unroll
      for (int u = 0; u < 6; ++u) vr[u] = feat[(size_t)(n * 6 + u) * 48 + 47];
      float s0 = vr[0]+vr[1]+vr[2]+vr[3]+vr[4]+vr[5];
#pragma unroll
      for (int u = 0; u < 6; ++u) { vr[u] = (s0 == 0.f) ? 1.f : vr[u]; mc[u] = vr[u]; }
#pragma unroll
      for (int u = 0; u < 6; ++u) vr[u] *= occ[n * 6 + u];
      float s2 = vr[0]+vr[1]+vr[2]+vr[3]+vr[4]+vr[5];
#pragma unroll
      for (int u = 0; u < 6; ++u) m6[u] = ((s2 == 0.f) ? 1.f : vr[u]) * mc[u];
    } else {
#pragma unroll
      for (int u = 0; u < 6; ++u) m6[u] = 1.f;
    }
#pragma unroll
    for (int u = 0; u < 6; ++u) mskS[wid][lane * 6 + u] = m6[u];
  }

  // ---- stage feat -> bf16 A-tile in B1 (16 rows x k32, k=21..31 zero) ----
  if (lane < 24) {
    int r12 = lane >> 1, half = lane & 1;
    int s = r12 / 6, v = r12 - s * 6;
    int n = n0 + s;
    int row = s * 8 + v;
    unsigned short* dst = B1 + row * 40 + half * 16;
    if (n < ntot) {
      const float* fb = feat + (size_t)(n * 6 + v) * 48;
      if (half == 0) {
        float4 fA = *(const float4*)(fb + 24);
        float4 fB = *(const float4*)(fb + 28);
        float4 fC = *(const float4*)(fb + 32);
        float4 fD = *(const float4*)(fb + 36);
        dst[0]  = bfc(fb[47]);
        dst[1]  = bfc(fA.x); dst[2]  = bfc(fA.y); dst[3]  = bfc(fA.z); dst[4]  = bfc(fA.w);
        dst[5]  = bfc(fB.x); dst[6]  = bfc(fB.y); dst[7]  = bfc(fB.z); dst[8]  = bfc(fB.w);
        dst[9]  = bfc(fC.x); dst[10] = bfc(fC.y); dst[11] = bfc(fC.z); dst[12] = bfc(fC.w);
        dst[13] = bfc(fD.x); dst[14] = bfc(fD.y); dst[15] = bfc(fD.z);
      } else {
        float4 fE = *(const float4*)(fb + 40);
        dst[0] = bfc(fb[39]);
        dst[1] = bfc(fE.x); dst[2] = bfc(fE.y); dst[3] = bfc(fE.z); dst[4] = bfc(fE.w);
#pragma unroll
        for (int j = 5; j < 16; ++j) dst[j] = 0;
      }
    } else {
#pragma unroll
      for (int j = 0; j < 16; ++j) dst[j] = 0;
    }
  } else if (lane < 40) {
    int pr = (lane - 24) >> 2, q = (lane - 24) & 3;
    int row = (pr >> 1) * 8 + 6 + (pr & 1);
    unsigned short* dst = B1 + row * 40 + q * 8;
#pragma unroll
    for (int j = 0; j < 8; ++j) dst[j] = 0;
  }
  __syncthreads();   // WTL(wtok) + B1 A-tiles ready

  // ---- token embedding: one MFMA pair + ELU epilogue -> B0 ----
  {
    s16x8 a = *(const s16x8*)(B1 + c * 40 + (gq << 3));
    f32x4 c0 = {0.f,0.f,0.f,0.f}, c1 = c0;
    c0 = mfma16(a, ldB32(WTL, 0, c, gq), c0);
    c1 = mfma16(a, ldB32(WTL, 1, c, gq), c1);
    float b0v = tokb[c], b1v = tokb[c + 16];
#pragma unroll
    for (int i = 0; i < 4; ++i) {
      int row = gq * 4 + i;
      B0[row * 40 + c]      = bfc(elu_f(c0[i] + b0v));
      B0[row * 40 + c + 16] = bfc(elu_f(c1[i] + b1v));
    }
  }
  __builtin_amdgcn_wave_barrier();

  // ---- transformer layers (barrier-free, wave-local) ----
  for (int l = 0; l < 4; ++l) {
    const unsigned short* wl = wsq + l * 6144;

    // QKV: one M-tile, 6 MFMAs
    {
      s16x8 a = *(const s16x8*)(B0 + c * 40 + (gq << 3));
      f32x4 cq0 = {0.f,0.f,0.f,0.f}, cq1 = cq0, ck0 = cq0, ck1 = cq0, cv0 = cq0, cv1 = cq0;
      cq0 = mfma16(a, ldB32(wl,        0, c, gq), cq0);
      cq1 = mfma16(a, ldB32(wl,        1, c, gq), cq1);
      ck0 = mfma16(a, ldB32(wl + 1024, 0, c, gq), ck0);
      ck1 = mfma16(a, ldB32(wl + 1024, 1, c, gq), ck1);
      cv0 = mfma16(a, ldB32(wl + 2048, 0, c, gq), cv0);
      cv1 = mfma16(a, ldB32(wl + 2048, 1, c, gq), cv1);
#pragma unroll
      for (int i = 0; i < 4; ++i) {
        int ro = (gq * 4 + i) * 40;
        B1[ro + c] = bfc(cq0[i]); B1[ro + c + 16] = bfc(cq1[i]);
        B2[ro + c] = bfc(ck0[i]); B2[ro + c + 16] = bfc(ck1[i]);
        B3[ro + c] = bfc(cv0[i]); B3[ro + c + 16] = bfc(cv1[i]);
      }
    }
    __builtin_amdgcn_wave_barrier();

    // attention: 48 lane jobs (s, q, h)
    if (lane < 48) {
      int s = lane / 24, t = lane - s * 24, q = t >> 2, h = t & 3;
      s16x8 qf = *(const s16x8*)(B1 + (s * 8 + q) * 40 + h * 8);
      float qv[8];
#pragma unroll
      for (int i = 0; i < 8; ++i) qv[i] = fbc((unsigned short)qf[i]);
      float p6[6];
#pragma unroll
      for (int u = 0; u < 6; ++u) {
        s16x8 kf = *(const s16x8*)(B2 + (s * 8 + u) * 40 + h * 8);
        float d = 0.f;
#pragma unroll
        for (int i = 0; i < 8; ++i) d += qv[i] * fbc((unsigned short)kf[i]);
        p6[u] = (mskS[wid][s * 6 + u] == 0.f) ? -INFINITY : d * ATTN_SCALE;
      }
      float mx = p6[0];
#pragma unroll
      for (int u = 1; u < 6; ++u) mx = fmaxf(mx, p6[u]);
      float sum = 0.f;
#pragma unroll
      for (int u = 0; u < 6; ++u) { float e = __expf(p6[u] - mx); p6[u] = e; sum += e; }
      float inv = 1.f / sum;
      float o[8];
#pragma unroll
      for (int i = 0; i < 8; ++i) o[i] = 0.f;
#pragma unroll
      for (int u = 0; u < 6; ++u) {
        s16x8 vf = *(const s16x8*)(B3 + (s * 8 + u) * 40 + h * 8);
        float pw = p6[u] * inv;
#pragma unroll
        for (int i = 0; i < 8; ++i) o[i] += pw * fbc((unsigned short)vf[i]);
      }
      unsigned short* op = B1 + (s * 8 + q) * 40 + h * 8;
#pragma unroll
      for (int i = 0; i < 8; ++i) op[i] = bfc(o[i]);
    }
    __builtin_amdgcn_wave_barrier();

    // X = LN1(O @ Wo + res[B0]) -> B2
    {
      s16x8 a = *(const s16x8*)(B1 + c * 40 + (gq << 3));
      f32x4 c0 = {0.f,0.f,0.f,0.f}, c1 = c0;
      c0 = mfma16(a, ldB32(wl + 3072, 0, c, gq), c0);
      c1 = mfma16(a, ldB32(wl + 3072, 1, c, gq), c1);
      float g0 = ln1g[l*32 + c], g1 = ln1g[l*32 + c + 16];
      float bb0 = ln1b[l*32 + c], bb1 = ln1b[l*32 + c + 16];
#pragma unroll
      for (int i = 0; i < 4; ++i) {
        int row = gq * 4 + i;
        float x0 = c0[i] + fbc(B0[row * 40 + c]);
        float x1 = c1[i] + fbc(B0[row * 40 + c + 16]);
        float s = x0 + x1, ss = x0 * x0 + x1 * x1;
#pragma unroll
        for (int m = 1; m < 16; m <<= 1) {
          s  += __shfl_xor(s,  m, 64);
          ss += __shfl_xor(ss, m, 64);
        }
        float mean = s * 0.03125f;
        float var  = fmaxf(ss * 0.03125f - mean * mean, 0.f);
        float rr   = rsqrtf(var + 1e-6f);
        B2[row * 40 + c]      = bfc((x0 - mean) * rr * g0 + bb0);
        B2[row * 40 + c + 16] = bfc((x1 - mean) * rr * g1 + bb1);
      }
    }
    __builtin_amdgcn_wave_barrier();

    // H = relu(X @ W1 + b1) -> B3
    {
      s16x8 a = *(const s16x8*)(B2 + c * 40 + (gq << 3));
      f32x4 c0 = {0.f,0.f,0.f,0.f}, c1 = c0;
      c0 = mfma16(a, ldB32(wl + 4096, 0, c, gq), c0);
      c1 = mfma16(a, ldB32(wl + 4096, 1, c, gq), c1);
      float bi0 = fb1[l*32 + c], bi1 = fb1[l*32 + c + 16];
#pragma unroll
      for (int i = 0; i < 4; ++i) {
        int row = gq * 4 + i;
        B3[row * 40 + c]      = bfc(fmaxf(c0[i] + bi0, 0.f));
        B3[row * 40 + c + 16] = bfc(fmaxf(c1[i] + bi1, 0.f));
      }
    }
    __builtin_amdgcn_wave_barrier();

    // T' = LN2(H @ W2 + b2 + X[B2]) -> B0
    {
      s16x8 a = *(const s16x8*)(B3 + c * 40 + (gq << 3));
      f32x4 c0 = {0.f,0.f,0.f,0.f}, c1 = c0;
      c0 = mfma16(a, ldB32(wl + 5120, 0, c, gq), c0);
      c1 = mfma16(a, ldB32(wl + 5120, 1, c, gq), c1);
      float g0 = ln2g[l*32 + c], g1 = ln2g[l*32 + c + 16];
      float bb0 = ln2b[l*32 + c], bb1 = ln2b[l*32 + c + 16];
      float bi0 = fb2[l*32 + c], bi1 = fb2[l*32 + c + 16];
#pragma unroll
      for (int i = 0; i < 4; ++i) {
        int row = gq * 4 + i;
        float x0 = c0[i] + bi0 + fbc(B2[row * 40 + c]);
        float x1 = c1[i] + bi1 + fbc(B2[row * 40 + c + 16]);
        float s = x0 + x1, ss = x0 * x0 + x1 * x1;
#pragma unroll
        for (int m = 1; m < 16; m <<= 1) {
          s  += __shfl_xor(s,  m, 64);
          ss += __shfl_xor(ss, m, 64);
        }
        float mean = s * 0.03125f;
        float var  = fmaxf(ss * 0.03125f - mean * mean, 0.f);
        float rr   = rsqrtf(var + 1e-6f);
        B0[row * 40 + c]      = bfc((x0 - mean) * rr * g0 + bb0);
        B0[row * 40 + c + 16] = bfc((x1 - mean) * rr * g1 + bb1);
      }
    }
    __builtin_amdgcn_wave_barrier();
  }

  // ---- head: block = 16 samples = one M=16 tile ----
  __syncthreads();

  // stage wt3 -> WTL: WT3[n(32)][k(96)], n>=20 zero (consumed after >=1 barrier)
  for (int t = tid; t < 3072; t += 512) {
    int n = t / 96, k = t - n * 96;
    WTL[t] = (n < 20) ? bfc(fc3w[k * 20 + n]) : (unsigned short)0;
  }

  // fc1: A-frag sample = c, k = (v=ck)*32.. ; 12 n-tiles over 8 waves
  {
    s16x8 a6[6];
#pragma unroll
    for (int ck = 0; ck < 6; ++ck)
      a6[ck] = *(const s16x8*)(SB0 + (c >> 1) * WSLICE + ((c & 1) * 8 + ck) * 40 + (gq << 3));
    int nt = wid;
    f32x4 acc = {0.f,0.f,0.f,0.f};
#pragma unroll
    for (int ck = 0; ck < 6; ++ck)
      acc = mfma16(a6[ck], *(const s16x8*)(wt1 + (nt*16 + c) * 192 + ck*32 + (gq << 3)), acc);
    float bi = fc1b[nt * 16 + c];
    if (wid < 4) {
      int nt2 = wid + 8;
      f32x4 acc2 = {0.f,0.f,0.f,0.f};
#pragma unroll
      for (int ck = 0; ck < 6; ++ck)
        acc2 = mfma16(a6[ck], *(const s16x8*)(wt1 + (nt2*16 + c) * 192 + ck*32 + (gq << 3)), acc2);
      float bi2 = fc1b[nt2 * 16 + c];
#pragma unroll
      for (int i = 0; i < 4; ++i) {
        unsigned short* ep = e1 + (gq * 4 + i) * 200 + nt * 16 + c;
        ep[0]   = bfc(elu_f(acc[i] + bi));
        ep[128] = bfc(elu_f(acc2[i] + bi2));
      }
    } else {
#pragma unroll
      for (int i = 0; i < 4; ++i)
        e1[(gq * 4 + i) * 200 + nt * 16 + c] = bfc(elu_f(acc[i] + bi));
    }
  }
  __syncthreads();

  // fc2: 6 n-tiles over waves 0..5
  if (wid < 6) {
    s16x8 h6[6];
#pragma unroll
    for (int ck = 0; ck < 6; ++ck)
      h6[ck] = *(const s16x8*)(e1 + c * 200 + ck * 32 + (gq << 3));
    int nt = wid;
    f32x4 acc = {0.f,0.f,0.f,0.f};
#pragma unroll
    for (int ck = 0; ck < 6; ++ck)
      acc = mfma16(h6[ck], *(const s16x8*)(wt2 + (nt*16 + c) * 192 + ck*32 + (gq << 3)), acc);
    float bi = fc2b[nt * 16 + c];
    int base = nt * 16 + c;
#pragma unroll
    for (int i = 0; i < 4; ++i)
      e2[(gq * 4 + i) * 104 + base] = bfc(elu_f(acc[i] + bi));
  }
  __syncthreads();

  // fc3: M=16 x N=20(pad32) x K=96 on waves 6,7 (3 MFMAs each)
  if (wid >= 6) {
    int nt = wid - 6;
    s16x8 a3[3];
#pragma unroll
    for (int ck = 0; ck < 3; ++ck)
      a3[ck] = *(const s16x8*)(e2 + c * 104 + ck * 32 + (gq << 3));
    f32x4 acc = {0.f,0.f,0.f,0.f};
#pragma unroll
    for (int ck = 0; ck < 3; ++ck)
      acc = mfma16(a3[ck], *(const s16x8*)(WTL + (nt*16 + c) * 96 + ck*32 + (gq << 3)), acc);
    int col = nt * 16 + c;
    if (col < 20) {
      float bi = fc3b[col];
#pragma unroll
      for (int i = 0; i < 4; ++i) {
        int n = n0b + gq * 4 + i;
        if (n < ntot) outp[(size_t)n * 20 + col] = fmaxf(acc[i] + bi, 0.f);
      }
    }
  }
}

extern "C" void kernel_launch(void* const* d_in, const int* in_sizes, int n_in,
                              void* d_out, int out_size, void* d_ws, size_t ws_size,
                              hipStream_t stream)
{
  const float* feat = (const float*)d_in[0];
  const float* occ  = (const float*)d_in[1];
  const float* tokw = (const float*)d_in[2];
  const float* tokb = (const float*)d_in[3];
  const float* wq   = (const float*)d_in[4];
  const float* wk   = (const float*)d_in[5];
  const float* wv   = (const float*)d_in[6];
  const float* wo   = (const float*)d_in[7];
  const float* ln1g = (const float*)d_in[8];
  const float* ln1b = (const float*)d_in[9];
  const float* fw1  = (const float*)d_in[10];
  const float* fb1  = (const float*)d_in[11];
  const float* fw2  = (const float*)d_in[12];
  const float* fb2  = (const float*)d_in[13];
  const float* ln2g = (const float*)d_in[14];
  const float* ln2b = (const float*)d_in[15];
  const float* fc1w = (const float*)d_in[16];
  const float* fc1b = (const float*)d_in[17];
  const float* fc2w = (const float*)d_in[18];
  const float* fc2b = (const float*)d_in[19];
  const float* fc3w = (const float*)d_in[20];
  const float* fc3b = (const float*)d_in[21];
  float* outp = (float*)d_out;

  unsigned short* ws = (unsigned short*)d_ws;
  const int ntot = in_sizes[0] / 288;

  hipLaunchKernelGGL(prep_kernel, dim3(128), dim3(256), 0, stream,
                     wq, wk, wv, wo, fw1, fw2, fc1w, fc2w, ws);

  const int grid = (ntot + 15) / 16;
  hipLaunchKernelGGL(sem_main, dim3(grid), dim3(512), 0, stream,
                     feat, occ, tokw, tokb, ln1g, ln1b, fb1, fb2, ln2g, ln2b,
                     fc1b, fc2b, fc3w, fc3b,
                     ws, ws + 24576, ws + 61440,
                     outp, ntot);
}

// Round 7
// 437.746 us; speedup vs baseline: 11.9923x; 1.1427x over previous
//
#include <hip/hip_runtime.h>
#include <hip/hip_bf16.h>
#include <math.h>

// Semantic predictor: wave-local bf16-MFMA transformer + fused MFMA head.
// 2 samples (12 real + 4 pad rows) = one 16-row M-tile per wave; barrier-free
// transformer phases (wave-private LDS slices). Round 7: LDS diet to 40960 B
// (4 blocks/CU): head buffers aliased into dead Q/K regions, WSLICE 648->640,
// attention masks in registers. __launch_bounds__(512,8) for 8 waves/SIMD.

typedef __attribute__((ext_vector_type(8))) short s16x8;
typedef __attribute__((ext_vector_type(4))) float f32x4;

#define ATTN_SCALE 0.35355339059327373f
#define WSLICE 640   // wave LDS slice stride in shorts (16 rows x 40)

__device__ __forceinline__ unsigned short bfc(float x) {
  __hip_bfloat16 h = __float2bfloat16(x);
  return __builtin_bit_cast(unsigned short, h);
}
__device__ __forceinline__ float fbc(unsigned short u) {
  union { unsigned v; float f; } w; w.v = ((unsigned)u) << 16;
  return w.f;
}
__device__ __forceinline__ float elu_f(float x) { return x > 0.f ? x : __expf(x) - 1.f; }

__device__ __forceinline__ f32x4 mfma16(s16x8 a, s16x8 b, f32x4 c) {
  return __builtin_amdgcn_mfma_f32_16x16x32_bf16(a, b, c, 0, 0, 0);
}
// B fragment from bf16 WT[n][32]: n = nt*16 + c, k = gq*8..+8
__device__ __forceinline__ s16x8 ldB32(const unsigned short* __restrict__ wt, int nt, int c, int gq) {
  return *(const s16x8*)(wt + (nt * 16 + c) * 32 + (gq << 3));
}

// ---------------- weight prep: f32 -> bf16, transposed (159,744 B) ----------------
__global__ void prep_kernel(const float* __restrict__ wq, const float* __restrict__ wk,
                            const float* __restrict__ wv, const float* __restrict__ wo,
                            const float* __restrict__ w1, const float* __restrict__ w2,
                            const float* __restrict__ fc1w, const float* __restrict__ fc2w,
                            unsigned short* __restrict__ ws)
{
  int i = blockIdx.x * blockDim.x + threadIdx.x;
  int stride = gridDim.x * blockDim.x;
  for (int t = i; t < 24576; t += stride) {       // [l][mat][n][k] <- mat[l][k][n]
    int lm = t >> 10;
    int l = lm / 6, m = lm - l * 6;
    int j = t & 1023, n = j >> 5, k = j & 31;
    const float* mp;
    if      (m == 0) mp = wq;
    else if (m == 1) mp = wk;
    else if (m == 2) mp = wv;
    else if (m == 3) mp = wo;
    else if (m == 4) mp = w1;
    else             mp = w2;
    ws[t] = bfc(mp[l * 1024 + k * 32 + n]);
  }
  for (int t = i; t < 36864; t += stride) {       // WT1[n(192)][k(192)]
    int n = t / 192, k = t - n * 192;
    ws[24576 + t] = bfc(fc1w[k * 192 + n]);
  }
  for (int t = i; t < 18432; t += stride) {       // WT2[n(96)][k(192)]
    int n = t / 192, k = t - n * 192;
    ws[61440 + t] = bfc(fc2w[k * 96 + n]);
  }
}

// ---------------- main fused kernel ----------------
__global__ __launch_bounds__(512, 8)
void sem_main(const float* __restrict__ feat, const float* __restrict__ occ,
              const float* __restrict__ tokw, const float* __restrict__ tokb,
              const float* __restrict__ ln1g, const float* __restrict__ ln1b,
              const float* __restrict__ fb1,  const float* __restrict__ fb2,
              const float* __restrict__ ln2g, const float* __restrict__ ln2b,
              const float* __restrict__ fc1b, const float* __restrict__ fc2b,
              const float* __restrict__ fc3w, const float* __restrict__ fc3b,
              const unsigned short* __restrict__ wsq,   // [l][mat][32][32]
              const unsigned short* __restrict__ wt1,   // [192][192]
              const unsigned short* __restrict__ wt2,   // [96][192]
              float* __restrict__ outp, int ntot)
{
  // 40960 B total. Regions (shorts): B0 @0, B1 @5120, B2 @10240, B3 @15360
  // (each 8 wave-slices x 640). Head aliases: e1 @5120 (3200), e2 @8320 (1664),
  // WTL @10240 (3072) -- live only when Q/K/X regions are dead.
  __shared__ unsigned short SH[20480];

  const int tid  = threadIdx.x;
  const int lane = tid & 63;
  const int wid  = tid >> 6;
  const int c    = lane & 15;
  const int gq   = lane >> 4;
  const int n0b  = blockIdx.x * 16;
  const int n0   = n0b + wid * 2;

  unsigned short* B0 = SH          + wid * WSLICE;
  unsigned short* B1 = SH +  5120 + wid * WSLICE;
  unsigned short* B2 = SH + 10240 + wid * WSLICE;
  unsigned short* B3 = SH + 15360 + wid * WSLICE;
  unsigned short* e1  = SH + 5120;
  unsigned short* e2  = SH + 8320;
  unsigned short* WTL = SH + 10240;

  // ---- stage wtok -> WTL[0..1024): WT_tok[n][32], k>=21 zero ----
  for (int t = tid; t < 1024; t += 512) {
    int n = t >> 5, k = t & 31;
    WTL[t] = (k < 21) ? bfc(tokw[k * 32 + n]) : (unsigned short)0;
  }

  // ---- masks in registers: each lane computes its attention-sample's masks ----
  float msk6[6];
  {
    int s_att = (lane >= 24 && lane < 48) ? 1 : 0;
    int nm = n0 + s_att;
    if (nm < ntot) {
      float vr[6], mc[6];
#pragma unroll
      for (int u = 0; u < 6; ++u) vr[u] = feat[(size_t)(nm * 6 + u) * 48 + 47];
      float s0 = vr[0]+vr[1]+vr[2]+vr[3]+vr[4]+vr[5];
#pragma unroll
      for (int u = 0; u < 6; ++u) { vr[u] = (s0 == 0.f) ? 1.f : vr[u]; mc[u] = vr[u]; }
#pragma unroll
      for (int u = 0; u < 6; ++u) vr[u] *= occ[nm * 6 + u];
      float s2 = vr[0]+vr[1]+vr[2]+vr[3]+vr[4]+vr[5];
#pragma unroll
      for (int u = 0; u < 6; ++u) msk6[u] = ((s2 == 0.f) ? 1.f : vr[u]) * mc[u];
    } else {
#pragma unroll
      for (int u = 0; u < 6; ++u) msk6[u] = 1.f;
    }
  }

  // ---- stage feat -> bf16 A-tile in B1 (16 rows x k32, k=21..31 zero) ----
  if (lane < 24) {
    int r12 = lane >> 1, half = lane & 1;
    int s = r12 / 6, v = r12 - s * 6;
    int n = n0 + s;
    int row = s * 8 + v;
    unsigned short* dst = B1 + row * 40 + half * 16;
    if (n < ntot) {
      const float* fb = feat + (size_t)(n * 6 + v) * 48;
      if (half == 0) {
        float4 fA = *(const float4*)(fb + 24);
        float4 fB = *(const float4*)(fb + 28);
        float4 fC = *(const float4*)(fb + 32);
        float4 fD = *(const float4*)(fb + 36);
        dst[0]  = bfc(fb[47]);
        dst[1]  = bfc(fA.x); dst[2]  = bfc(fA.y); dst[3]  = bfc(fA.z); dst[4]  = bfc(fA.w);
        dst[5]  = bfc(fB.x); dst[6]  = bfc(fB.y); dst[7]  = bfc(fB.z); dst[8]  = bfc(fB.w);
        dst[9]  = bfc(fC.x); dst[10] = bfc(fC.y); dst[11] = bfc(fC.z); dst[12] = bfc(fC.w);
        dst[13] = bfc(fD.x); dst[14] = bfc(fD.y); dst[15] = bfc(fD.z);
      } else {
        float4 fE = *(const float4*)(fb + 40);
        dst[0] = bfc(fb[39]);
        dst[1] = bfc(fE.x); dst[2] = bfc(fE.y); dst[3] = bfc(fE.z); dst[4] = bfc(fE.w);
#pragma unroll
        for (int j = 5; j < 16; ++j) dst[j] = 0;
      }
    } else {
#pragma unroll
      for (int j = 0; j < 16; ++j) dst[j] = 0;
    }
  } else if (lane < 40) {
    int pr = (lane - 24) >> 2, q = (lane - 24) & 3;
    int row = (pr >> 1) * 8 + 6 + (pr & 1);
    unsigned short* dst = B1 + row * 40 + q * 8;
#pragma unroll
    for (int j = 0; j < 8; ++j) dst[j] = 0;
  }
  __syncthreads();   // WTL(wtok) + B1 A-tiles ready

  // ---- token embedding: one MFMA pair + ELU epilogue -> B0 ----
  {
    s16x8 a = *(const s16x8*)(B1 + c * 40 + (gq << 3));
    f32x4 c0 = {0.f,0.f,0.f,0.f}, c1 = c0;
    c0 = mfma16(a, ldB32(WTL, 0, c, gq), c0);
    c1 = mfma16(a, ldB32(WTL, 1, c, gq), c1);
    float b0v = tokb[c], b1v = tokb[c + 16];
#pragma unroll
    for (int i = 0; i < 4; ++i) {
      int row = gq * 4 + i;
      B0[row * 40 + c]      = bfc(elu_f(c0[i] + b0v));
      B0[row * 40 + c + 16] = bfc(elu_f(c1[i] + b1v));
    }
  }
  __syncthreads();   // all waves done reading WTL before layer-0 K/V overwrite it

  // ---- transformer layers (barrier-free, wave-local) ----
  for (int l = 0; l < 4; ++l) {
    const unsigned short* wl = wsq + l * 6144;

    // QKV: one M-tile, 6 MFMAs
    {
      s16x8 a = *(const s16x8*)(B0 + c * 40 + (gq << 3));
      f32x4 cq0 = {0.f,0.f,0.f,0.f}, cq1 = cq0, ck0 = cq0, ck1 = cq0, cv0 = cq0, cv1 = cq0;
      cq0 = mfma16(a, ldB32(wl,        0, c, gq), cq0);
      cq1 = mfma16(a, ldB32(wl,        1, c, gq), cq1);
      ck0 = mfma16(a, ldB32(wl + 1024, 0, c, gq), ck0);
      ck1 = mfma16(a, ldB32(wl + 1024, 1, c, gq), ck1);
      cv0 = mfma16(a, ldB32(wl + 2048, 0, c, gq), cv0);
      cv1 = mfma16(a, ldB32(wl + 2048, 1, c, gq), cv1);
#pragma unroll
      for (int i = 0; i < 4; ++i) {
        int ro = (gq * 4 + i) * 40;
        B1[ro + c] = bfc(cq0[i]); B1[ro + c + 16] = bfc(cq1[i]);
        B2[ro + c] = bfc(ck0[i]); B2[ro + c + 16] = bfc(ck1[i]);
        B3[ro + c] = bfc(cv0[i]); B3[ro + c + 16] = bfc(cv1[i]);
      }
    }
    __builtin_amdgcn_wave_barrier();

    // attention: 48 lane jobs (s, q, h)
    if (lane < 48) {
      int s = lane / 24, t = lane - s * 24, q = t >> 2, h = t & 3;
      s16x8 qf = *(const s16x8*)(B1 + (s * 8 + q) * 40 + h * 8);
      float qv[8];
#pragma unroll
      for (int i = 0; i < 8; ++i) qv[i] = fbc((unsigned short)qf[i]);
      float p6[6];
#pragma unroll
      for (int u = 0; u < 6; ++u) {
        s16x8 kf = *(const s16x8*)(B2 + (s * 8 + u) * 40 + h * 8);
        float d = 0.f;
#pragma unroll
        for (int i = 0; i < 8; ++i) d += qv[i] * fbc((unsigned short)kf[i]);
        p6[u] = (msk6[u] == 0.f) ? -INFINITY : d * ATTN_SCALE;
      }
      float mx = p6[0];
#pragma unroll
      for (int u = 1; u < 6; ++u) mx = fmaxf(mx, p6[u]);
      float sum = 0.f;
#pragma unroll
      for (int u = 0; u < 6; ++u) { float e = __expf(p6[u] - mx); p6[u] = e; sum += e; }
      float inv = 1.f / sum;
      float o[8];
#pragma unroll
      for (int i = 0; i < 8; ++i) o[i] = 0.f;
#pragma unroll
      for (int u = 0; u < 6; ++u) {
        s16x8 vf = *(const s16x8*)(B3 + (s * 8 + u) * 40 + h * 8);
        float pw = p6[u] * inv;
#pragma unroll
        for (int i = 0; i < 8; ++i) o[i] += pw * fbc((unsigned short)vf[i]);
      }
      unsigned short* op = B1 + (s * 8 + q) * 40 + h * 8;
#pragma unroll
      for (int i = 0; i < 8; ++i) op[i] = bfc(o[i]);
    }
    __builtin_amdgcn_wave_barrier();

    // X = LN1(O @ Wo + res[B0]) -> B2
    {
      s16x8 a = *(const s16x8*)(B1 + c * 40 + (gq << 3));
      f32x4 c0 = {0.f,0.f,0.f,0.f}, c1 = c0;
      c0 = mfma16(a, ldB32(wl + 3072, 0, c, gq), c0);
      c1 = mfma16(a, ldB32(wl + 3072, 1, c, gq), c1);
      float g0 = ln1g[l*32 + c], g1 = ln1g[l*32 + c + 16];
      float bb0 = ln1b[l*32 + c], bb1 = ln1b[l*32 + c + 16];
#pragma unroll
      for (int i = 0; i < 4; ++i) {
        int row = gq * 4 + i;
        float x0 = c0[i] + fbc(B0[row * 40 + c]);
        float x1 = c1[i] + fbc(B0[row * 40 + c + 16]);
        float s = x0 + x1, ss = x0 * x0 + x1 * x1;
#pragma unroll
        for (int m = 1; m < 16; m <<= 1) {
          s  += __shfl_xor(s,  m, 64);
          ss += __shfl_xor(ss, m, 64);
        }
        float mean = s * 0.03125f;
        float var  = fmaxf(ss * 0.03125f - mean * mean, 0.f);
        float rr   = rsqrtf(var + 1e-6f);
        B2[row * 40 + c]      = bfc((x0 - mean) * rr * g0 + bb0);
        B2[row * 40 + c + 16] = bfc((x1 - mean) * rr * g1 + bb1);
      }
    }
    __builtin_amdgcn_wave_barrier();

    // H = relu(X @ W1 + b1) -> B3
    {
      s16x8 a = *(const s16x8*)(B2 + c * 40 + (gq << 3));
      f32x4 c0 = {0.f,0.f,0.f,0.f}, c1 = c0;
      c0 = mfma16(a, ldB32(wl + 4096, 0, c, gq), c0);
      c1 = mfma16(a, ldB32(wl + 4096, 1, c, gq), c1);
      float bi0 = fb1[l*32 + c], bi1 = fb1[l*32 + c + 16];
#pragma unroll
      for (int i = 0; i < 4; ++i) {
        int row = gq * 4 + i;
        B3[row * 40 + c]      = bfc(fmaxf(c0[i] + bi0, 0.f));
        B3[row * 40 + c + 16] = bfc(fmaxf(c1[i] + bi1, 0.f));
      }
    }
    __builtin_amdgcn_wave_barrier();

    // T' = LN2(H @ W2 + b2 + X[B2]) -> B0
    {
      s16x8 a = *(const s16x8*)(B3 + c * 40 + (gq << 3));
      f32x4 c0 = {0.f,0.f,0.f,0.f}, c1 = c0;
      c0 = mfma16(a, ldB32(wl + 5120, 0, c, gq), c0);
      c1 = mfma16(a, ldB32(wl + 5120, 1, c, gq), c1);
      float g0 = ln2g[l*32 + c], g1 = ln2g[l*32 + c + 16];
      float bb0 = ln2b[l*32 + c], bb1 = ln2b[l*32 + c + 16];
      float bi0 = fb2[l*32 + c], bi1 = fb2[l*32 + c + 16];
#pragma unroll
      for (int i = 0; i < 4; ++i) {
        int row = gq * 4 + i;
        float x0 = c0[i] + bi0 + fbc(B2[row * 40 + c]);
        float x1 = c1[i] + bi1 + fbc(B2[row * 40 + c + 16]);
        float s = x0 + x1, ss = x0 * x0 + x1 * x1;
#pragma unroll
        for (int m = 1; m < 16; m <<= 1) {
          s  += __shfl_xor(s,  m, 64);
          ss += __shfl_xor(ss, m, 64);
        }
        float mean = s * 0.03125f;
        float var  = fmaxf(ss * 0.03125f - mean * mean, 0.f);
        float rr   = rsqrtf(var + 1e-6f);
        B0[row * 40 + c]      = bfc((x0 - mean) * rr * g0 + bb0);
        B0[row * 40 + c + 16] = bfc((x1 - mean) * rr * g1 + bb1);
      }
    }
    __builtin_amdgcn_wave_barrier();
  }

  // ---- head: block = 16 samples = one M=16 tile ----
  __syncthreads();   // transformer done; Q/K/X regions dead -> alias e1/e2/WTL

  // stage wt3 -> WTL: WT3[n(32)][k(96)], n>=20 zero
  for (int t = tid; t < 3072; t += 512) {
    int n = t / 96, k = t - n * 96;
    WTL[t] = (n < 20) ? bfc(fc3w[k * 20 + n]) : (unsigned short)0;
  }

  // fc1: A-frag sample = c, k = (v=ck)*32.. ; 12 n-tiles over 8 waves
  {
    s16x8 a6[6];
#pragma unroll
    for (int ck = 0; ck < 6; ++ck)
      a6[ck] = *(const s16x8*)(SH + (c >> 1) * WSLICE + ((c & 1) * 8 + ck) * 40 + (gq << 3));
    int nt = wid;
    f32x4 acc = {0.f,0.f,0.f,0.f};
#pragma unroll
    for (int ck = 0; ck < 6; ++ck)
      acc = mfma16(a6[ck], *(const s16x8*)(wt1 + (nt*16 + c) * 192 + ck*32 + (gq << 3)), acc);
    float bi = fc1b[nt * 16 + c];
    if (wid < 4) {
      int nt2 = wid + 8;
      f32x4 acc2 = {0.f,0.f,0.f,0.f};
#pragma unroll
      for (int ck = 0; ck < 6; ++ck)
        acc2 = mfma16(a6[ck], *(const s16x8*)(wt1 + (nt2*16 + c) * 192 + ck*32 + (gq << 3)), acc2);
      float bi2 = fc1b[nt2 * 16 + c];
#pragma unroll
      for (int i = 0; i < 4; ++i) {
        unsigned short* ep = e1 + (gq * 4 + i) * 200 + nt * 16 + c;
        ep[0]   = bfc(elu_f(acc[i] + bi));
        ep[128] = bfc(elu_f(acc2[i] + bi2));
      }
    } else {
#pragma unroll
      for (int i = 0; i < 4; ++i)
        e1[(gq * 4 + i) * 200 + nt * 16 + c] = bfc(elu_f(acc[i] + bi));
    }
  }
  __syncthreads();

  // fc2: 6 n-tiles over waves 0..5
  if (wid < 6) {
    s16x8 h6[6];
#pragma unroll
    for (int ck = 0; ck < 6; ++ck)
      h6[ck] = *(const s16x8*)(e1 + c * 200 + ck * 32 + (gq << 3));
    int nt = wid;
    f32x4 acc = {0.f,0.f,0.f,0.f};
#pragma unroll
    for (int ck = 0; ck < 6; ++ck)
      acc = mfma16(h6[ck], *(const s16x8*)(wt2 + (nt*16 + c) * 192 + ck*32 + (gq << 3)), acc);
    float bi = fc2b[nt * 16 + c];
    int base = nt * 16 + c;
#pragma unroll
    for (int i = 0; i < 4; ++i)
      e2[(gq * 4 + i) * 104 + base] = bfc(elu_f(acc[i] + bi));
  }
  __syncthreads();

  // fc3: M=16 x N=20(pad32) x K=96 on waves 6,7 (3 MFMAs each)
  if (wid >= 6) {
    int nt = wid - 6;
    s16x8 a3[3];
#pragma unroll
    for (int ck = 0; ck < 3; ++ck)
      a3[ck] = *(const s16x8*)(e2 + c * 104 + ck * 32 + (gq << 3));
    f32x4 acc = {0.f,0.f,0.f,0.f};
#pragma unroll
    for (int ck = 0; ck < 3; ++ck)
      acc = mfma16(a3[ck], *(const s16x8*)(WTL + (nt*16 + c) * 96 + ck*32 + (gq << 3)), acc);
    int col = nt * 16 + c;
    if (col < 20) {
      float bi = fc3b[col];
#pragma unroll
      for (int i = 0; i < 4; ++i) {
        int n = n0b + gq * 4 + i;
        if (n < ntot) outp[(size_t)n * 20 + col] = fmaxf(acc[i] + bi, 0.f);
      }
    }
  }
}

extern "C" void kernel_launch(void* const* d_in, const int* in_sizes, int n_in,
                              void* d_out, int out_size, void* d_ws, size_t ws_size,
                              hipStream_t stream)
{
  const float* feat = (const float*)d_in[0];
  const float* occ  = (const float*)d_in[1];
  const float* tokw = (const float*)d_in[2];
  const float* tokb = (const float*)d_in[3];
  const float* wq   = (const float*)d_in[4];
  const float* wk   = (const float*)d_in[5];
  const float* wv   = (const float*)d_in[6];
  const float* wo   = (const float*)d_in[7];
  const float* ln1g = (const float*)d_in[8];
  const float* ln1b = (const float*)d_in[9];
  const float* fw1  = (const float*)d_in[10];
  const float* fb1  = (const float*)d_in[11];
  const float* fw2  = (const float*)d_in[12];
  const float* fb2  = (const float*)d_in[13];
  const float* ln2g = (const float*)d_in[14];
  const float* ln2b = (const float*)d_in[15];
  const float* fc1w = (const float*)d_in[16];
  const float* fc1b = (const float*)d_in[17];
  const float* fc2w = (const float*)d_in[18];
  const float* fc2b = (const float*)d_in[19];
  const float* fc3w = (const float*)d_in[20];
  const float* fc3b = (const float*)d_in[21];
  float* outp = (float*)d_out;

  unsigned short* ws = (unsigned short*)d_ws;
  const int ntot = in_sizes[0] / 288;

  hipLaunchKernelGGL(prep_kernel, dim3(128), dim3(256), 0, stream,
                     wq, wk, wv, wo, fw1, fw2, fc1w, fc2w, ws);

  const int grid = (ntot + 15) / 16;
  hipLaunchKernelGGL(sem_main, dim3(grid), dim3(512), 0, stream,
                     feat, occ, tokw, tokb, ln1g, ln1b, fb1, fb2, ln2g, ln2b,
                     fc1b, fc2b, fc3w, fc3b,
                     ws, ws + 24576, ws + 61440,
                     outp, ntot);
}

// Round 8
// 430.291 us; speedup vs baseline: 12.2000x; 1.0173x over previous
//
#include <hip/hip_runtime.h>
#include <hip/hip_bf16.h>
#include <math.h>

// Semantic predictor: wave-local bf16-MFMA transformer + fused MFMA head.
// 2 samples (12 real + 4 pad rows) = one 16-row M-tile per wave; barrier-free
// transformer phases (wave-private LDS slices). Round 8: paired-column
// epilogues -- transformer WT n-maps are interleaved (tile nt row n -> orig
// col 2n+nt) so each lane's two outputs are adjacent cols (2c,2c+1):
// packed bf16x2 LDS writes, b32 residual reads, float2 bias/gain loads.
// LDS activation layout stays original-column-order (A-frags/attention/head
// unchanged).

typedef __attribute__((ext_vector_type(8))) short s16x8;
typedef __attribute__((ext_vector_type(4))) float f32x4;

#define ATTN_SCALE 0.35355339059327373f
#define WSLICE 640   // wave LDS slice stride in shorts (16 rows x 40)

__device__ __forceinline__ unsigned short bfc(float x) {
  __hip_bfloat16 h = __float2bfloat16(x);
  return __builtin_bit_cast(unsigned short, h);
}
// pack 2 f32 -> 2 bf16 in one u32 (lo -> bits[15:0])
__device__ __forceinline__ unsigned pk2(float lo, float hi) {
  float2 f; f.x = lo; f.y = hi;
  union { __hip_bfloat162 h; unsigned u; } cv;
  cv.h = __float22bfloat162_rn(f);
  return cv.u;
}
__device__ __forceinline__ float fbc(unsigned short u) {
  union { unsigned v; float f; } w; w.v = ((unsigned)u) << 16;
  return w.f;
}
__device__ __forceinline__ float f_lo(unsigned u) {
  union { unsigned v; float f; } w; w.v = u << 16; return w.f;
}
__device__ __forceinline__ float f_hi(unsigned u) {
  union { unsigned v; float f; } w; w.v = u & 0xffff0000u; return w.f;
}
__device__ __forceinline__ float elu_f(float x) { return x > 0.f ? x : __expf(x) - 1.f; }

__device__ __forceinline__ f32x4 mfma16(s16x8 a, s16x8 b, f32x4 c) {
  return __builtin_amdgcn_mfma_f32_16x16x32_bf16(a, b, c, 0, 0, 0);
}
// B fragment from bf16 WT[n][32]: n = nt*16 + c, k = gq*8..+8
__device__ __forceinline__ s16x8 ldB32(const unsigned short* __restrict__ wt, int nt, int c, int gq) {
  return *(const s16x8*)(wt + (nt * 16 + c) * 32 + (gq << 3));
}

// ---------------- weight prep: f32 -> bf16, transposed (159,744 B) ----------------
__global__ void prep_kernel(const float* __restrict__ wq, const float* __restrict__ wk,
                            const float* __restrict__ wv, const float* __restrict__ wo,
                            const float* __restrict__ w1, const float* __restrict__ w2,
                            const float* __restrict__ fc1w, const float* __restrict__ fc2w,
                            unsigned short* __restrict__ ws)
{
  int i = blockIdx.x * blockDim.x + threadIdx.x;
  int stride = gridDim.x * blockDim.x;
  // transformer mats: [l][mat][n][k], INTERLEAVED n: tile nt row nn -> orig col 2*nn+nt
  for (int t = i; t < 24576; t += stride) {
    int lm = t >> 10;
    int l = lm / 6, m = lm - l * 6;
    int j = t & 1023, n = j >> 5, k = j & 31;
    int col = 2 * (n & 15) + (n >> 4);
    const float* mp;
    if      (m == 0) mp = wq;
    else if (m == 1) mp = wk;
    else if (m == 2) mp = wv;
    else if (m == 3) mp = wo;
    else if (m == 4) mp = w1;
    else             mp = w2;
    ws[t] = bfc(mp[l * 1024 + k * 32 + col]);
  }
  for (int t = i; t < 36864; t += stride) {       // WT1[n(192)][k(192)] (original order)
    int n = t / 192, k = t - n * 192;
    ws[24576 + t] = bfc(fc1w[k * 192 + n]);
  }
  for (int t = i; t < 18432; t += stride) {       // WT2[n(96)][k(192)]
    int n = t / 192, k = t - n * 192;
    ws[61440 + t] = bfc(fc2w[k * 96 + n]);
  }
}

// ---------------- main fused kernel ----------------
__global__ __launch_bounds__(512, 8)
void sem_main(const float* __restrict__ feat, const float* __restrict__ occ,
              const float* __restrict__ tokw, const float* __restrict__ tokb,
              const float* __restrict__ ln1g, const float* __restrict__ ln1b,
              const float* __restrict__ fb1,  const float* __restrict__ fb2,
              const float* __restrict__ ln2g, const float* __restrict__ ln2b,
              const float* __restrict__ fc1b, const float* __restrict__ fc2b,
              const float* __restrict__ fc3w, const float* __restrict__ fc3b,
              const unsigned short* __restrict__ wsq,   // [l][mat][32][32] interleaved-n
              const unsigned short* __restrict__ wt1,   // [192][192]
              const unsigned short* __restrict__ wt2,   // [96][192]
              float* __restrict__ outp, int ntot)
{
  // 40960 B total. B0 @0, B1 @5120, B2 @10240, B3 @15360 (8 slices x 640 each).
  // Head aliases: e1 @5120, e2 @8320, WTL @10240 (live only when Q/K dead).
  __shared__ unsigned short SH[20480];

  const int tid  = threadIdx.x;
  const int lane = tid & 63;
  const int wid  = tid >> 6;
  const int c    = lane & 15;
  const int gq   = lane >> 4;
  const int n0b  = blockIdx.x * 16;
  const int n0   = n0b + wid * 2;

  unsigned short* B0 = SH          + wid * WSLICE;
  unsigned short* B1 = SH +  5120 + wid * WSLICE;
  unsigned short* B2 = SH + 10240 + wid * WSLICE;
  unsigned short* B3 = SH + 15360 + wid * WSLICE;
  unsigned short* e1  = SH + 5120;
  unsigned short* e2  = SH + 8320;
  unsigned short* WTL = SH + 10240;

  // ---- stage wtok -> WTL (interleaved-n, k>=21 zero) ----
  for (int t = tid; t < 1024; t += 512) {
    int n = t >> 5, k = t & 31;
    int col = 2 * (n & 15) + (n >> 4);
    WTL[t] = (k < 21) ? bfc(tokw[k * 32 + col]) : (unsigned short)0;
  }

  // ---- masks in registers ----
  float msk6[6];
  {
    int s_att = (lane >= 24 && lane < 48) ? 1 : 0;
    int nm = n0 + s_att;
    if (nm < ntot) {
      float vr[6], mc[6];
#pragma unroll
      for (int u = 0; u < 6; ++u) vr[u] = feat[(size_t)(nm * 6 + u) * 48 + 47];
      float s0 = vr[0]+vr[1]+vr[2]+vr[3]+vr[4]+vr[5];
#pragma unroll
      for (int u = 0; u < 6; ++u) { vr[u] = (s0 == 0.f) ? 1.f : vr[u]; mc[u] = vr[u]; }
#pragma unroll
      for (int u = 0; u < 6; ++u) vr[u] *= occ[nm * 6 + u];
      float s2 = vr[0]+vr[1]+vr[2]+vr[3]+vr[4]+vr[5];
#pragma unroll
      for (int u = 0; u < 6; ++u) msk6[u] = ((s2 == 0.f) ? 1.f : vr[u]) * mc[u];
    } else {
#pragma unroll
      for (int u = 0; u < 6; ++u) msk6[u] = 1.f;
    }
  }

  // ---- stage feat -> bf16 A-tile in B1 (packed b32 writes) ----
  if (lane < 24) {
    int r12 = lane >> 1, half = lane & 1;
    int s = r12 / 6, v = r12 - s * 6;
    int n = n0 + s;
    int row = s * 8 + v;
    unsigned* dst = (unsigned*)(B1 + row * 40) + half * 8;
    if (n < ntot) {
      const float* fb = feat + (size_t)(n * 6 + v) * 48;
      if (half == 0) {
        // k = 0..15: vis, fb[24..38]
        float4 fA = *(const float4*)(fb + 24);
        float4 fB = *(const float4*)(fb + 28);
        float4 fC = *(const float4*)(fb + 32);
        float4 fD = *(const float4*)(fb + 36);
        dst[0] = pk2(fb[47], fA.x); dst[1] = pk2(fA.y, fA.z);
        dst[2] = pk2(fA.w, fB.x);  dst[3] = pk2(fB.y, fB.z);
        dst[4] = pk2(fB.w, fC.x);  dst[5] = pk2(fC.y, fC.z);
        dst[6] = pk2(fC.w, fD.x);  dst[7] = pk2(fD.y, fD.z);
      } else {
        // k = 16..20: fb[39..43], rest zero
        float4 fE = *(const float4*)(fb + 40);
        dst[0] = pk2(fb[39], fE.x); dst[1] = pk2(fE.y, fE.z);
        dst[2] = pk2(fE.w, 0.f);
        dst[3] = 0u; dst[4] = 0u; dst[5] = 0u; dst[6] = 0u; dst[7] = 0u;
      }
    } else {
#pragma unroll
      for (int j = 0; j < 8; ++j) dst[j] = 0u;
    }
  } else if (lane < 40) {
    int pr = (lane - 24) >> 2, q = (lane - 24) & 3;
    int row = (pr >> 1) * 8 + 6 + (pr & 1);
    unsigned* dst = (unsigned*)(B1 + row * 40) + q * 4;
    dst[0] = 0u; dst[1] = 0u; dst[2] = 0u; dst[3] = 0u;
  }
  __syncthreads();   // WTL(wtok) + B1 A-tiles ready

  // ---- token embedding: MFMA pair + ELU, paired-col store -> B0 ----
  {
    s16x8 a = *(const s16x8*)(B1 + c * 40 + (gq << 3));
    f32x4 c0 = {0.f,0.f,0.f,0.f}, c1 = c0;
    c0 = mfma16(a, ldB32(WTL, 0, c, gq), c0);
    c1 = mfma16(a, ldB32(WTL, 1, c, gq), c1);
    float2 tb = *(const float2*)(tokb + 2 * c);
#pragma unroll
    for (int i = 0; i < 4; ++i) {
      int row = gq * 4 + i;
      *(unsigned*)(B0 + row * 40 + 2 * c) = pk2(elu_f(c0[i] + tb.x), elu_f(c1[i] + tb.y));
    }
  }
  __syncthreads();   // all waves done reading WTL before layer-0 K/V overwrite it

  // ---- transformer layers (barrier-free, wave-local) ----
  for (int l = 0; l < 4; ++l) {
    const unsigned short* wl = wsq + l * 6144;

    // QKV: one M-tile, 6 MFMAs, paired-col stores
    {
      s16x8 a = *(const s16x8*)(B0 + c * 40 + (gq << 3));
      f32x4 cq0 = {0.f,0.f,0.f,0.f}, cq1 = cq0, ck0 = cq0, ck1 = cq0, cv0 = cq0, cv1 = cq0;
      cq0 = mfma16(a, ldB32(wl,        0, c, gq), cq0);
      cq1 = mfma16(a, ldB32(wl,        1, c, gq), cq1);
      ck0 = mfma16(a, ldB32(wl + 1024, 0, c, gq), ck0);
      ck1 = mfma16(a, ldB32(wl + 1024, 1, c, gq), ck1);
      cv0 = mfma16(a, ldB32(wl + 2048, 0, c, gq), cv0);
      cv1 = mfma16(a, ldB32(wl + 2048, 1, c, gq), cv1);
#pragma unroll
      for (int i = 0; i < 4; ++i) {
        int ro = (gq * 4 + i) * 40 + 2 * c;
        *(unsigned*)(B1 + ro) = pk2(cq0[i], cq1[i]);
        *(unsigned*)(B2 + ro) = pk2(ck0[i], ck1[i]);
        *(unsigned*)(B3 + ro) = pk2(cv0[i], cv1[i]);
      }
    }
    __builtin_amdgcn_wave_barrier();

    // attention: 48 lane jobs (s, q, h)
    if (lane < 48) {
      int s = lane / 24, t = lane - s * 24, q = t >> 2, h = t & 3;
      s16x8 qf = *(const s16x8*)(B1 + (s * 8 + q) * 40 + h * 8);
      float qv[8];
#pragma unroll
      for (int i = 0; i < 8; ++i) qv[i] = fbc((unsigned short)qf[i]);
      float p6[6];
#pragma unroll
      for (int u = 0; u < 6; ++u) {
        s16x8 kf = *(const s16x8*)(B2 + (s * 8 + u) * 40 + h * 8);
        float d = 0.f;
#pragma unroll
        for (int i = 0; i < 8; ++i) d += qv[i] * fbc((unsigned short)kf[i]);
        p6[u] = (msk6[u] == 0.f) ? -INFINITY : d * ATTN_SCALE;
      }
      float mx = p6[0];
#pragma unroll
      for (int u = 1; u < 6; ++u) mx = fmaxf(mx, p6[u]);
      float sum = 0.f;
#pragma unroll
      for (int u = 0; u < 6; ++u) { float e = __expf(p6[u] - mx); p6[u] = e; sum += e; }
      float inv = 1.f / sum;
      float o[8];
#pragma unroll
      for (int i = 0; i < 8; ++i) o[i] = 0.f;
#pragma unroll
      for (int u = 0; u < 6; ++u) {
        s16x8 vf = *(const s16x8*)(B3 + (s * 8 + u) * 40 + h * 8);
        float pw = p6[u] * inv;
#pragma unroll
        for (int i = 0; i < 8; ++i) o[i] += pw * fbc((unsigned short)vf[i]);
      }
      unsigned* op = (unsigned*)(B1 + (s * 8 + q) * 40 + h * 8);
      op[0] = pk2(o[0], o[1]); op[1] = pk2(o[2], o[3]);
      op[2] = pk2(o[4], o[5]); op[3] = pk2(o[6], o[7]);
    }
    __builtin_amdgcn_wave_barrier();

    // X = LN1(O @ Wo + res[B0]) -> B2
    {
      s16x8 a = *(const s16x8*)(B1 + c * 40 + (gq << 3));
      f32x4 c0 = {0.f,0.f,0.f,0.f}, c1 = c0;
      c0 = mfma16(a, ldB32(wl + 3072, 0, c, gq), c0);
      c1 = mfma16(a, ldB32(wl + 3072, 1, c, gq), c1);
      float2 g2 = *(const float2*)(ln1g + l*32 + 2*c);
      float2 b2 = *(const float2*)(ln1b + l*32 + 2*c);
#pragma unroll
      for (int i = 0; i < 4; ++i) {
        int row = gq * 4 + i;
        unsigned rp = *(const unsigned*)(B0 + row * 40 + 2 * c);
        float x0 = c0[i] + f_lo(rp);
        float x1 = c1[i] + f_hi(rp);
        float s = x0 + x1, ss = x0 * x0 + x1 * x1;
#pragma unroll
        for (int m = 1; m < 16; m <<= 1) {
          s  += __shfl_xor(s,  m, 64);
          ss += __shfl_xor(ss, m, 64);
        }
        float mean = s * 0.03125f;
        float var  = fmaxf(ss * 0.03125f - mean * mean, 0.f);
        float rr   = rsqrtf(var + 1e-6f);
        *(unsigned*)(B2 + row * 40 + 2 * c) =
            pk2((x0 - mean) * rr * g2.x + b2.x, (x1 - mean) * rr * g2.y + b2.y);
      }
    }
    __builtin_amdgcn_wave_barrier();

    // H = relu(X @ W1 + b1) -> B3
    {
      s16x8 a = *(const s16x8*)(B2 + c * 40 + (gq << 3));
      f32x4 c0 = {0.f,0.f,0.f,0.f}, c1 = c0;
      c0 = mfma16(a, ldB32(wl + 4096, 0, c, gq), c0);
      c1 = mfma16(a, ldB32(wl + 4096, 1, c, gq), c1);
      float2 bi = *(const float2*)(fb1 + l*32 + 2*c);
#pragma unroll
      for (int i = 0; i < 4; ++i) {
        int row = gq * 4 + i;
        *(unsigned*)(B3 + row * 40 + 2 * c) =
            pk2(fmaxf(c0[i] + bi.x, 0.f), fmaxf(c1[i] + bi.y, 0.f));
      }
    }
    __builtin_amdgcn_wave_barrier();

    // T' = LN2(H @ W2 + b2 + X[B2]) -> B0
    {
      s16x8 a = *(const s16x8*)(B3 + c * 40 + (gq << 3));
      f32x4 c0 = {0.f,0.f,0.f,0.f}, c1 = c0;
      c0 = mfma16(a, ldB32(wl + 5120, 0, c, gq), c0);
      c1 = mfma16(a, ldB32(wl + 5120, 1, c, gq), c1);
      float2 g2 = *(const float2*)(ln2g + l*32 + 2*c);
      float2 b2 = *(const float2*)(ln2b + l*32 + 2*c);
      float2 bi = *(const float2*)(fb2 + l*32 + 2*c);
#pragma unroll
      for (int i = 0; i < 4; ++i) {
        int row = gq * 4 + i;
        unsigned rp = *(const unsigned*)(B2 + row * 40 + 2 * c);
        float x0 = c0[i] + bi.x + f_lo(rp);
        float x1 = c1[i] + bi.y + f_hi(rp);
        float s = x0 + x1, ss = x0 * x0 + x1 * x1;
#pragma unroll
        for (int m = 1; m < 16; m <<= 1) {
          s  += __shfl_xor(s,  m, 64);
          ss += __shfl_xor(ss, m, 64);
        }
        float mean = s * 0.03125f;
        float var  = fmaxf(ss * 0.03125f - mean * mean, 0.f);
        float rr   = rsqrtf(var + 1e-6f);
        *(unsigned*)(B0 + row * 40 + 2 * c) =
            pk2((x0 - mean) * rr * g2.x + b2.x, (x1 - mean) * rr * g2.y + b2.y);
      }
    }
    __builtin_amdgcn_wave_barrier();
  }

  // ---- head: block = 16 samples = one M=16 tile ----
  __syncthreads();   // transformer done; Q/K/X regions dead -> alias e1/e2/WTL

  // stage wt3 -> WTL: WT3[n(32)][k(96)], n>=20 zero (original order)
  for (int t = tid; t < 3072; t += 512) {
    int n = t / 96, k = t - n * 96;
    WTL[t] = (n < 20) ? bfc(fc3w[k * 20 + n]) : (unsigned short)0;
  }

  // fc1: A-frag sample = c, k = (v=ck)*32.. ; 12 n-tiles over 8 waves
  {
    s16x8 a6[6];
#pragma unroll
    for (int ck = 0; ck < 6; ++ck)
      a6[ck] = *(const s16x8*)(SH + (c >> 1) * WSLICE + ((c & 1) * 8 + ck) * 40 + (gq << 3));
    int nt = wid;
    f32x4 acc = {0.f,0.f,0.f,0.f};
#pragma unroll
    for (int ck = 0; ck < 6; ++ck)
      acc = mfma16(a6[ck], *(const s16x8*)(wt1 + (nt*16 + c) * 192 + ck*32 + (gq << 3)), acc);
    float bi = fc1b[nt * 16 + c];
    if (wid < 4) {
      int nt2 = wid + 8;
      f32x4 acc2 = {0.f,0.f,0.f,0.f};
#pragma unroll
      for (int ck = 0; ck < 6; ++ck)
        acc2 = mfma16(a6[ck], *(const s16x8*)(wt1 + (nt2*16 + c) * 192 + ck*32 + (gq << 3)), acc2);
      float bi2 = fc1b[nt2 * 16 + c];
#pragma unroll
      for (int i = 0; i < 4; ++i) {
        unsigned short* ep = e1 + (gq * 4 + i) * 200 + nt * 16 + c;
        ep[0]   = bfc(elu_f(acc[i] + bi));
        ep[128] = bfc(elu_f(acc2[i] + bi2));
      }
    } else {
#pragma unroll
      for (int i = 0; i < 4; ++i)
        e1[(gq * 4 + i) * 200 + nt * 16 + c] = bfc(elu_f(acc[i] + bi));
    }
  }
  __syncthreads();

  // fc2: 6 n-tiles over waves 0..5
  if (wid < 6) {
    s16x8 h6[6];
#pragma unroll
    for (int ck = 0; ck < 6; ++ck)
      h6[ck] = *(const s16x8*)(e1 + c * 200 + ck * 32 + (gq << 3));
    int nt = wid;
    f32x4 acc = {0.f,0.f,0.f,0.f};
#pragma unroll
    for (int ck = 0; ck < 6; ++ck)
      acc = mfma16(h6[ck], *(const s16x8*)(wt2 + (nt*16 + c) * 192 + ck*32 + (gq << 3)), acc);
    float bi = fc2b[nt * 16 + c];
    int base = nt * 16 + c;
#pragma unroll
    for (int i = 0; i < 4; ++i)
      e2[(gq * 4 + i) * 104 + base] = bfc(elu_f(acc[i] + bi));
  }
  __syncthreads();

  // fc3: M=16 x N=20(pad32) x K=96 on waves 6,7 (3 MFMAs each)
  if (wid >= 6) {
    int nt = wid - 6;
    s16x8 a3[3];
#pragma unroll
    for (int ck = 0; ck < 3; ++ck)
      a3[ck] = *(const s16x8*)(e2 + c * 104 + ck * 32 + (gq << 3));
    f32x4 acc = {0.f,0.f,0.f,0.f};
#pragma unroll
    for (int ck = 0; ck < 3; ++ck)
      acc = mfma16(a3[ck], *(const s16x8*)(WTL + (nt*16 + c) * 96 + ck*32 + (gq << 3)), acc);
    int col = nt * 16 + c;
    if (col < 20) {
      float bi = fc3b[col];
#pragma unroll
      for (int i = 0; i < 4; ++i) {
        int n = n0b + gq * 4 + i;
        if (n < ntot) outp[(size_t)n * 20 + col] = fmaxf(acc[i] + bi, 0.f);
      }
    }
  }
}

extern "C" void kernel_launch(void* const* d_in, const int* in_sizes, int n_in,
                              void* d_out, int out_size, void* d_ws, size_t ws_size,
                              hipStream_t stream)
{
  const float* feat = (const float*)d_in[0];
  const float* occ  = (const float*)d_in[1];
  const float* tokw = (const float*)d_in[2];
  const float* tokb = (const float*)d_in[3];
  const float* wq   = (const float*)d_in[4];
  const float* wk   = (const float*)d_in[5];
  const float* wv   = (const float*)d_in[6];
  const float* wo   = (const float*)d_in[7];
  const float* ln1g = (const float*)d_in[8];
  const float* ln1b = (const float*)d_in[9];
  const float* fw1  = (const float*)d_in[10];
  const float* fb1  = (const float*)d_in[11];
  const float* fw2  = (const float*)d_in[12];
  const float* fb2  = (const float*)d_in[13];
  const float* ln2g = (const float*)d_in[14];
  const float* ln2b = (const float*)d_in[15];
  const float* fc1w = (const float*)d_in[16];
  const float* fc1b = (const float*)d_in[17];
  const float* fc2w = (const float*)d_in[18];
  const float* fc2b = (const float*)d_in[19];
  const float* fc3w = (const float*)d_in[20];
  const float* fc3b = (const float*)d_in[21];
  float* outp = (float*)d_out;

  unsigned short* ws = (unsigned short*)d_ws;
  const int ntot = in_sizes[0] / 288;

  hipLaunchKernelGGL(prep_kernel, dim3(128), dim3(256), 0, stream,
                     wq, wk, wv, wo, fw1, fw2, fc1w, fc2w, ws);

  const int grid = (ntot + 15) / 16;
  hipLaunchKernelGGL(sem_main, dim3(grid), dim3(512), 0, stream,
                     feat, occ, tokw, tokb, ln1g, ln1b, fb1, fb2, ln2g, ln2b,
                     fc1b, fc2b, fc3w, fc3b,
                     ws, ws + 24576, ws + 61440,
                     outp, ntot);
}

// Round 9
// 418.918 us; speedup vs baseline: 12.5312x; 1.0271x over previous
//
#include <hip/hip_runtime.h>
#include <hip/hip_bf16.h>
#include <math.h>

// Semantic predictor: wave-local bf16-MFMA transformer + fused MFMA head.
// Round 9: LDS-pipe diet. LN reductions via DPP-fused butterfly (no ds_swizzle);
// residuals carried in registers (no LDS residual reads). Paired-column
// epilogues (interleaved WT n-map) from round 8 retained.

typedef __attribute__((ext_vector_type(8))) short s16x8;
typedef __attribute__((ext_vector_type(4))) float f32x4;

#define ATTN_SCALE 0.35355339059327373f
#define WSLICE 640   // wave LDS slice stride in shorts (16 rows x 40)

__device__ __forceinline__ unsigned short bfc(float x) {
  __hip_bfloat16 h = __float2bfloat16(x);
  return __builtin_bit_cast(unsigned short, h);
}
// pack 2 f32 -> 2 bf16 in one u32 (lo -> bits[15:0])
__device__ __forceinline__ unsigned pk2(float lo, float hi) {
  float2 f; f.x = lo; f.y = hi;
  union { __hip_bfloat162 h; unsigned u; } cv;
  cv.h = __float22bfloat162_rn(f);
  return cv.u;
}
__device__ __forceinline__ float fbc(unsigned short u) {
  union { unsigned v; float f; } w; w.v = ((unsigned)u) << 16;
  return w.f;
}
__device__ __forceinline__ float elu_f(float x) { return x > 0.f ? x : __expf(x) - 1.f; }

// 16-lane (DPP16 row) butterfly sum, zero DS ops:
// stages xor1 (quad_perm [1,0,3,2]=0xB1), xor2 ([2,3,0,1]=0x4E),
// xor7 (row_half_mirror=0x141), xor15 (row_mirror=0x140).
__device__ __forceinline__ float row16_sum(float x) {
  int v;
  v = __builtin_amdgcn_update_dpp(0, __builtin_bit_cast(int, x), 0xB1,  0xF, 0xF, true);
  x += __builtin_bit_cast(float, v);
  v = __builtin_amdgcn_update_dpp(0, __builtin_bit_cast(int, x), 0x4E,  0xF, 0xF, true);
  x += __builtin_bit_cast(float, v);
  v = __builtin_amdgcn_update_dpp(0, __builtin_bit_cast(int, x), 0x141, 0xF, 0xF, true);
  x += __builtin_bit_cast(float, v);
  v = __builtin_amdgcn_update_dpp(0, __builtin_bit_cast(int, x), 0x140, 0xF, 0xF, true);
  x += __builtin_bit_cast(float, v);
  return x;
}

__device__ __forceinline__ f32x4 mfma16(s16x8 a, s16x8 b, f32x4 c) {
  return __builtin_amdgcn_mfma_f32_16x16x32_bf16(a, b, c, 0, 0, 0);
}
// B fragment from bf16 WT[n][32]: n = nt*16 + c, k = gq*8..+8
__device__ __forceinline__ s16x8 ldB32(const unsigned short* __restrict__ wt, int nt, int c, int gq) {
  return *(const s16x8*)(wt + (nt * 16 + c) * 32 + (gq << 3));
}

// ---------------- weight prep: f32 -> bf16, transposed (159,744 B) ----------------
__global__ void prep_kernel(const float* __restrict__ wq, const float* __restrict__ wk,
                            const float* __restrict__ wv, const float* __restrict__ wo,
                            const float* __restrict__ w1, const float* __restrict__ w2,
                            const float* __restrict__ fc1w, const float* __restrict__ fc2w,
                            unsigned short* __restrict__ ws)
{
  int i = blockIdx.x * blockDim.x + threadIdx.x;
  int stride = gridDim.x * blockDim.x;
  // transformer mats: [l][mat][n][k], INTERLEAVED n: tile nt row nn -> orig col 2*nn+nt
  for (int t = i; t < 24576; t += stride) {
    int lm = t >> 10;
    int l = lm / 6, m = lm - l * 6;
    int j = t & 1023, n = j >> 5, k = j & 31;
    int col = 2 * (n & 15) + (n >> 4);
    const float* mp;
    if      (m == 0) mp = wq;
    else if (m == 1) mp = wk;
    else if (m == 2) mp = wv;
    else if (m == 3) mp = wo;
    else if (m == 4) mp = w1;
    else             mp = w2;
    ws[t] = bfc(mp[l * 1024 + k * 32 + col]);
  }
  for (int t = i; t < 36864; t += stride) {       // WT1[n(192)][k(192)] (original order)
    int n = t / 192, k = t - n * 192;
    ws[24576 + t] = bfc(fc1w[k * 192 + n]);
  }
  for (int t = i; t < 18432; t += stride) {       // WT2[n(96)][k(192)]
    int n = t / 192, k = t - n * 192;
    ws[61440 + t] = bfc(fc2w[k * 96 + n]);
  }
}

// ---------------- main fused kernel ----------------
__global__ __launch_bounds__(512, 8)
void sem_main(const float* __restrict__ feat, const float* __restrict__ occ,
              const float* __restrict__ tokw, const float* __restrict__ tokb,
              const float* __restrict__ ln1g, const float* __restrict__ ln1b,
              const float* __restrict__ fb1,  const float* __restrict__ fb2,
              const float* __restrict__ ln2g, const float* __restrict__ ln2b,
              const float* __restrict__ fc1b, const float* __restrict__ fc2b,
              const float* __restrict__ fc3w, const float* __restrict__ fc3b,
              const unsigned short* __restrict__ wsq,   // [l][mat][32][32] interleaved-n
              const unsigned short* __restrict__ wt1,   // [192][192]
              const unsigned short* __restrict__ wt2,   // [96][192]
              float* __restrict__ outp, int ntot)
{
  // 40960 B total. B0 @0, B1 @5120, B2 @10240, B3 @15360 (8 slices x 640 each).
  // Head aliases: e1 @5120, e2 @8320, WTL @10240 (live only when Q/K dead).
  __shared__ unsigned short SH[20480];

  const int tid  = threadIdx.x;
  const int lane = tid & 63;
  const int wid  = tid >> 6;
  const int c    = lane & 15;
  const int gq   = lane >> 4;
  const int n0b  = blockIdx.x * 16;
  const int n0   = n0b + wid * 2;

  unsigned short* B0 = SH          + wid * WSLICE;
  unsigned short* B1 = SH +  5120 + wid * WSLICE;
  unsigned short* B2 = SH + 10240 + wid * WSLICE;
  unsigned short* B3 = SH + 15360 + wid * WSLICE;
  unsigned short* e1  = SH + 5120;
  unsigned short* e2  = SH + 8320;
  unsigned short* WTL = SH + 10240;

  // ---- stage wtok -> WTL (interleaved-n, k>=21 zero) ----
  for (int t = tid; t < 1024; t += 512) {
    int n = t >> 5, k = t & 31;
    int col = 2 * (n & 15) + (n >> 4);
    WTL[t] = (k < 21) ? bfc(tokw[k * 32 + col]) : (unsigned short)0;
  }

  // ---- masks in registers ----
  float msk6[6];
  {
    int s_att = (lane >= 24 && lane < 48) ? 1 : 0;
    int nm = n0 + s_att;
    if (nm < ntot) {
      float vr[6], mc[6];
#pragma unroll
      for (int u = 0; u < 6; ++u) vr[u] = feat[(size_t)(nm * 6 + u) * 48 + 47];
      float s0 = vr[0]+vr[1]+vr[2]+vr[3]+vr[4]+vr[5];
#pragma unroll
      for (int u = 0; u < 6; ++u) { vr[u] = (s0 == 0.f) ? 1.f : vr[u]; mc[u] = vr[u]; }
#pragma unroll
      for (int u = 0; u < 6; ++u) vr[u] *= occ[nm * 6 + u];
      float s2 = vr[0]+vr[1]+vr[2]+vr[3]+vr[4]+vr[5];
#pragma unroll
      for (int u = 0; u < 6; ++u) msk6[u] = ((s2 == 0.f) ? 1.f : vr[u]) * mc[u];
    } else {
#pragma unroll
      for (int u = 0; u < 6; ++u) msk6[u] = 1.f;
    }
  }

  // ---- stage feat -> bf16 A-tile in B1 (packed b32 writes) ----
  if (lane < 24) {
    int r12 = lane >> 1, half = lane & 1;
    int s = r12 / 6, v = r12 - s * 6;
    int n = n0 + s;
    int row = s * 8 + v;
    unsigned* dst = (unsigned*)(B1 + row * 40) + half * 8;
    if (n < ntot) {
      const float* fb = feat + (size_t)(n * 6 + v) * 48;
      if (half == 0) {
        float4 fA = *(const float4*)(fb + 24);
        float4 fB = *(const float4*)(fb + 28);
        float4 fC = *(const float4*)(fb + 32);
        float4 fD = *(const float4*)(fb + 36);
        dst[0] = pk2(fb[47], fA.x); dst[1] = pk2(fA.y, fA.z);
        dst[2] = pk2(fA.w, fB.x);  dst[3] = pk2(fB.y, fB.z);
        dst[4] = pk2(fB.w, fC.x);  dst[5] = pk2(fC.y, fC.z);
        dst[6] = pk2(fC.w, fD.x);  dst[7] = pk2(fD.y, fD.z);
      } else {
        float4 fE = *(const float4*)(fb + 40);
        dst[0] = pk2(fb[39], fE.x); dst[1] = pk2(fE.y, fE.z);
        dst[2] = pk2(fE.w, 0.f);
        dst[3] = 0u; dst[4] = 0u; dst[5] = 0u; dst[6] = 0u; dst[7] = 0u;
      }
    } else {
#pragma unroll
      for (int j = 0; j < 8; ++j) dst[j] = 0u;
    }
  } else if (lane < 40) {
    int pr = (lane - 24) >> 2, q = (lane - 24) & 3;
    int row = (pr >> 1) * 8 + 6 + (pr & 1);
    unsigned* dst = (unsigned*)(B1 + row * 40) + q * 4;
    dst[0] = 0u; dst[1] = 0u; dst[2] = 0u; dst[3] = 0u;
  }
  __syncthreads();   // WTL(wtok) + B1 A-tiles ready

  // residual pairs for rows gq*4+i, cols (2c, 2c+1), carried in registers
  float resL[4], resH[4];

  // ---- token embedding: MFMA pair + ELU, paired-col store -> B0 ----
  {
    s16x8 a = *(const s16x8*)(B1 + c * 40 + (gq << 3));
    f32x4 c0 = {0.f,0.f,0.f,0.f}, c1 = c0;
    c0 = mfma16(a, ldB32(WTL, 0, c, gq), c0);
    c1 = mfma16(a, ldB32(WTL, 1, c, gq), c1);
    float2 tb = *(const float2*)(tokb + 2 * c);
#pragma unroll
    for (int i = 0; i < 4; ++i) {
      int row = gq * 4 + i;
      float e0 = elu_f(c0[i] + tb.x), e1v = elu_f(c1[i] + tb.y);
      resL[i] = e0; resH[i] = e1v;
      *(unsigned*)(B0 + row * 40 + 2 * c) = pk2(e0, e1v);
    }
  }
  __syncthreads();   // all waves done reading WTL before layer-0 K/V overwrite it

  // ---- transformer layers (barrier-free, wave-local) ----
  for (int l = 0; l < 4; ++l) {
    const unsigned short* wl = wsq + l * 6144;

    // QKV: one M-tile, 6 MFMAs, paired-col stores
    {
      s16x8 a = *(const s16x8*)(B0 + c * 40 + (gq << 3));
      f32x4 cq0 = {0.f,0.f,0.f,0.f}, cq1 = cq0, ck0 = cq0, ck1 = cq0, cv0 = cq0, cv1 = cq0;
      cq0 = mfma16(a, ldB32(wl,        0, c, gq), cq0);
      cq1 = mfma16(a, ldB32(wl,        1, c, gq), cq1);
      ck0 = mfma16(a, ldB32(wl + 1024, 0, c, gq), ck0);
      ck1 = mfma16(a, ldB32(wl + 1024, 1, c, gq), ck1);
      cv0 = mfma16(a, ldB32(wl + 2048, 0, c, gq), cv0);
      cv1 = mfma16(a, ldB32(wl + 2048, 1, c, gq), cv1);
#pragma unroll
      for (int i = 0; i < 4; ++i) {
        int ro = (gq * 4 + i) * 40 + 2 * c;
        *(unsigned*)(B1 + ro) = pk2(cq0[i], cq1[i]);
        *(unsigned*)(B2 + ro) = pk2(ck0[i], ck1[i]);
        *(unsigned*)(B3 + ro) = pk2(cv0[i], cv1[i]);
      }
    }
    __builtin_amdgcn_wave_barrier();

    // attention: 48 lane jobs (s, q, h)
    if (lane < 48) {
      int s = lane / 24, t = lane - s * 24, q = t >> 2, h = t & 3;
      s16x8 qf = *(const s16x8*)(B1 + (s * 8 + q) * 40 + h * 8);
      float qv[8];
#pragma unroll
      for (int i = 0; i < 8; ++i) qv[i] = fbc((unsigned short)qf[i]);
      float p6[6];
#pragma unroll
      for (int u = 0; u < 6; ++u) {
        s16x8 kf = *(const s16x8*)(B2 + (s * 8 + u) * 40 + h * 8);
        float d = 0.f;
#pragma unroll
        for (int i = 0; i < 8; ++i) d += qv[i] * fbc((unsigned short)kf[i]);
        p6[u] = (msk6[u] == 0.f) ? -INFINITY : d * ATTN_SCALE;
      }
      float mx = p6[0];
#pragma unroll
      for (int u = 1; u < 6; ++u) mx = fmaxf(mx, p6[u]);
      float sum = 0.f;
#pragma unroll
      for (int u = 0; u < 6; ++u) { float e = __expf(p6[u] - mx); p6[u] = e; sum += e; }
      float inv = 1.f / sum;
      float o[8];
#pragma unroll
      for (int i = 0; i < 8; ++i) o[i] = 0.f;
#pragma unroll
      for (int u = 0; u < 6; ++u) {
        s16x8 vf = *(const s16x8*)(B3 + (s * 8 + u) * 40 + h * 8);
        float pw = p6[u] * inv;
#pragma unroll
        for (int i = 0; i < 8; ++i) o[i] += pw * fbc((unsigned short)vf[i]);
      }
      unsigned* op = (unsigned*)(B1 + (s * 8 + q) * 40 + h * 8);
      op[0] = pk2(o[0], o[1]); op[1] = pk2(o[2], o[3]);
      op[2] = pk2(o[4], o[5]); op[3] = pk2(o[6], o[7]);
    }
    __builtin_amdgcn_wave_barrier();

    float xL[4], xH[4];   // LN1 outputs (f32), residual for LN2

    // X = LN1(O @ Wo + res[regs]) -> B2
    {
      s16x8 a = *(const s16x8*)(B1 + c * 40 + (gq << 3));
      f32x4 c0 = {0.f,0.f,0.f,0.f}, c1 = c0;
      c0 = mfma16(a, ldB32(wl + 3072, 0, c, gq), c0);
      c1 = mfma16(a, ldB32(wl + 3072, 1, c, gq), c1);
      float2 g2 = *(const float2*)(ln1g + l*32 + 2*c);
      float2 b2 = *(const float2*)(ln1b + l*32 + 2*c);
#pragma unroll
      for (int i = 0; i < 4; ++i) {
        int row = gq * 4 + i;
        float x0 = c0[i] + resL[i];
        float x1 = c1[i] + resH[i];
        float s  = row16_sum(x0 + x1);
        float ss = row16_sum(x0 * x0 + x1 * x1);
        float mean = s * 0.03125f;
        float var  = fmaxf(ss * 0.03125f - mean * mean, 0.f);
        float rr   = rsqrtf(var + 1e-6f);
        float o0 = (x0 - mean) * rr * g2.x + b2.x;
        float o1 = (x1 - mean) * rr * g2.y + b2.y;
        xL[i] = o0; xH[i] = o1;
        *(unsigned*)(B2 + row * 40 + 2 * c) = pk2(o0, o1);
      }
    }
    __builtin_amdgcn_wave_barrier();

    // H = relu(X @ W1 + b1) -> B3
    {
      s16x8 a = *(const s16x8*)(B2 + c * 40 + (gq << 3));
      f32x4 c0 = {0.f,0.f,0.f,0.f}, c1 = c0;
      c0 = mfma16(a, ldB32(wl + 4096, 0, c, gq), c0);
      c1 = mfma16(a, ldB32(wl + 4096, 1, c, gq), c1);
      float2 bi = *(const float2*)(fb1 + l*32 + 2*c);
#pragma unroll
      for (int i = 0; i < 4; ++i) {
        int row = gq * 4 + i;
        *(unsigned*)(B3 + row * 40 + 2 * c) =
            pk2(fmaxf(c0[i] + bi.x, 0.f), fmaxf(c1[i] + bi.y, 0.f));
      }
    }
    __builtin_amdgcn_wave_barrier();

    // T' = LN2(H @ W2 + b2 + X[regs]) -> B0, residual regs updated
    {
      s16x8 a = *(const s16x8*)(B3 + c * 40 + (gq << 3));
      f32x4 c0 = {0.f,0.f,0.f,0.f}, c1 = c0;
      c0 = mfma16(a, ldB32(wl + 5120, 0, c, gq), c0);
      c1 = mfma16(a, ldB32(wl + 5120, 1, c, gq), c1);
      float2 g2 = *(const float2*)(ln2g + l*32 + 2*c);
      float2 b2 = *(const float2*)(ln2b + l*32 + 2*c);
      float2 bi = *(const float2*)(fb2 + l*32 + 2*c);
#pragma unroll
      for (int i = 0; i < 4; ++i) {
        int row = gq * 4 + i;
        float x0 = c0[i] + bi.x + xL[i];
        float x1 = c1[i] + bi.y + xH[i];
        float s  = row16_sum(x0 + x1);
        float ss = row16_sum(x0 * x0 + x1 * x1);
        float mean = s * 0.03125f;
        float var  = fmaxf(ss * 0.03125f - mean * mean, 0.f);
        float rr   = rsqrtf(var + 1e-6f);
        float o0 = (x0 - mean) * rr * g2.x + b2.x;
        float o1 = (x1 - mean) * rr * g2.y + b2.y;
        resL[i] = o0; resH[i] = o1;
        *(unsigned*)(B0 + row * 40 + 2 * c) = pk2(o0, o1);
      }
    }
    __builtin_amdgcn_wave_barrier();
  }

  // ---- head: block = 16 samples = one M=16 tile ----
  __syncthreads();   // transformer done; Q/K/X regions dead -> alias e1/e2/WTL

  // stage wt3 -> WTL: WT3[n(32)][k(96)], n>=20 zero (original order)
  for (int t = tid; t < 3072; t += 512) {
    int n = t / 96, k = t - n * 96;
    WTL[t] = (n < 20) ? bfc(fc3w[k * 20 + n]) : (unsigned short)0;
  }

  // fc1: A-frag sample = c, k = (v=ck)*32.. ; 12 n-tiles over 8 waves
  {
    s16x8 a6[6];
#pragma unroll
    for (int ck = 0; ck < 6; ++ck)
      a6[ck] = *(const s16x8*)(SH + (c >> 1) * WSLICE + ((c & 1) * 8 + ck) * 40 + (gq << 3));
    int nt = wid;
    f32x4 acc = {0.f,0.f,0.f,0.f};
#pragma unroll
    for (int ck = 0; ck < 6; ++ck)
      acc = mfma16(a6[ck], *(const s16x8*)(wt1 + (nt*16 + c) * 192 + ck*32 + (gq << 3)), acc);
    float bi = fc1b[nt * 16 + c];
    if (wid < 4) {
      int nt2 = wid + 8;
      f32x4 acc2 = {0.f,0.f,0.f,0.f};
#pragma unroll
      for (int ck = 0; ck < 6; ++ck)
        acc2 = mfma16(a6[ck], *(const s16x8*)(wt1 + (nt2*16 + c) * 192 + ck*32 + (gq << 3)), acc2);
      float bi2 = fc1b[nt2 * 16 + c];
#pragma unroll
      for (int i = 0; i < 4; ++i) {
        unsigned short* ep = e1 + (gq * 4 + i) * 200 + nt * 16 + c;
        ep[0]   = bfc(elu_f(acc[i] + bi));
        ep[128] = bfc(elu_f(acc2[i] + bi2));
      }
    } else {
#pragma unroll
      for (int i = 0; i < 4; ++i)
        e1[(gq * 4 + i) * 200 + nt * 16 + c] = bfc(elu_f(acc[i] + bi));
    }
  }
  __syncthreads();

  // fc2: 6 n-tiles over waves 0..5
  if (wid < 6) {
    s16x8 h6[6];
#pragma unroll
    for (int ck = 0; ck < 6; ++ck)
      h6[ck] = *(const s16x8*)(e1 + c * 200 + ck * 32 + (gq << 3));
    int nt = wid;
    f32x4 acc = {0.f,0.f,0.f,0.f};
#pragma unroll
    for (int ck = 0; ck < 6; ++ck)
      acc = mfma16(h6[ck], *(const s16x8*)(wt2 + (nt*16 + c) * 192 + ck*32 + (gq << 3)), acc);
    float bi = fc2b[nt * 16 + c];
    int base = nt * 16 + c;
#pragma unroll
    for (int i = 0; i < 4; ++i)
      e2[(gq * 4 + i) * 104 + base] = bfc(elu_f(acc[i] + bi));
  }
  __syncthreads();

  // fc3: M=16 x N=20(pad32) x K=96 on waves 6,7 (3 MFMAs each)
  if (wid >= 6) {
    int nt = wid - 6;
    s16x8 a3[3];
#pragma unroll
    for (int ck = 0; ck < 3; ++ck)
      a3[ck] = *(const s16x8*)(e2 + c * 104 + ck * 32 + (gq << 3));
    f32x4 acc = {0.f,0.f,0.f,0.f};
#pragma unroll
    for (int ck = 0; ck < 3; ++ck)
      acc = mfma16(a3[ck], *(const s16x8*)(WTL + (nt*16 + c) * 96 + ck*32 + (gq << 3)), acc);
    int col = nt * 16 + c;
    if (col < 20) {
      float bi = fc3b[col];
#pragma unroll
      for (int i = 0; i < 4; ++i) {
        int n = n0b + gq * 4 + i;
        if (n < ntot) outp[(size_t)n * 20 + col] = fmaxf(acc[i] + bi, 0.f);
      }
    }
  }
}

extern "C" void kernel_launch(void* const* d_in, const int* in_sizes, int n_in,
                              void* d_out, int out_size, void* d_ws, size_t ws_size,
                              hipStream_t stream)
{
  const float* feat = (const float*)d_in[0];
  const float* occ  = (const float*)d_in[1];
  const float* tokw = (const float*)d_in[2];
  const float* tokb = (const float*)d_in[3];
  const float* wq   = (const float*)d_in[4];
  const float* wk   = (const float*)d_in[5];
  const float* wv   = (const float*)d_in[6];
  const float* wo   = (const float*)d_in[7];
  const float* ln1g = (const float*)d_in[8];
  const float* ln1b = (const float*)d_in[9];
  const float* fw1  = (const float*)d_in[10];
  const float* fb1  = (const float*)d_in[11];
  const float* fw2  = (const float*)d_in[12];
  const float* fb2  = (const float*)d_in[13];
  const float* ln2g = (const float*)d_in[14];
  const float* ln2b = (const float*)d_in[15];
  const float* fc1w = (const float*)d_in[16];
  const float* fc1b = (const float*)d_in[17];
  const float* fc2w = (const float*)d_in[18];
  const float* fc2b = (const float*)d_in[19];
  const float* fc3w = (const float*)d_in[20];
  const float* fc3b = (const float*)d_in[21];
  float* outp = (float*)d_out;

  unsigned short* ws = (unsigned short*)d_ws;
  const int ntot = in_sizes[0] / 288;

  hipLaunchKernelGGL(prep_kernel, dim3(128), dim3(256), 0, stream,
                     wq, wk, wv, wo, fw1, fw2, fc1w, fc2w, ws);

  const int grid = (ntot + 15) / 16;
  hipLaunchKernelGGL(sem_main, dim3(grid), dim3(512), 0, stream,
                     feat, occ, tokw, tokb, ln1g, ln1b, fb1, fb2, ln2g, ln2b,
                     fc1b, fc2b, fc3w, fc3b,
                     ws, ws + 24576, ws + 61440,
                     outp, ntot);
}